// Round 5
// baseline (582.335 us; speedup 1.0000x reference)
//
#include <hip/hip_runtime.h>
#include <cstddef>
#include <cstdint>

#define HEADS 4
#define OUTC  40
#define NEG   0.2f
#define EPSV  1e-16f

typedef __bf16 bf16x8 __attribute__((ext_vector_type(8)));
typedef float  floatx4 __attribute__((ext_vector_type(4)));

__device__ __forceinline__ void split_bf16(float a, unsigned& hi, unsigned& lo) {
  unsigned u = __float_as_uint(a);
  hi = u >> 16;                                   // RTZ high bf16
  float hf = __uint_as_float(u & 0xFFFF0000u);
  lo = __float_as_uint(a - hf) >> 16;             // RTZ residual bf16
}

// async global->LDS DMA, 16B per lane. lds ptr must be wave-uniform base;
// HW writes lane i at base + i*16 (m97/m104).
__device__ __forceinline__ void dma16(const void* g, void* l) {
  __builtin_amdgcn_global_load_lds(
      (const __attribute__((address_space(1))) unsigned int*)g,
      (__attribute__((address_space(3))) unsigned int*)l, 16, 0, 0);
}

// ---------------- CSR build ----------------
__global__ void hist_k(const int* __restrict__ dst, int* __restrict__ cnt, int E) {
  int e = blockIdx.x * blockDim.x + threadIdx.x;
  if (e < E) atomicAdd(&cnt[dst[e]], 1);
}

__global__ __launch_bounds__(1024) void scanA_k(const int* __restrict__ cnt,
                                                int* __restrict__ rp,
                                                int* __restrict__ bsum, int n) {
  __shared__ int sh[1024];
  int i = blockIdx.x * 1024 + threadIdx.x;
  int v = (i < n) ? cnt[i] : 0;
  sh[threadIdx.x] = v;
  __syncthreads();
  for (int d = 1; d < 1024; d <<= 1) {
    int t = (threadIdx.x >= d) ? sh[threadIdx.x - d] : 0;
    __syncthreads();
    sh[threadIdx.x] += t;
    __syncthreads();
  }
  if (i < n) rp[i] = sh[threadIdx.x] - v;  // block-local exclusive
  if (threadIdx.x == 1023) bsum[blockIdx.x] = sh[1023];
}

// adds bsum prefix to rp (folds old scanB); rp[n] = total.
// R13: also zeroes cnt (used as scatter cursor) -- saves a memset launch.
__global__ void scanC_k(int* __restrict__ rp, const int* __restrict__ bsum,
                        int* __restrict__ cnt, int n, int nb) {
  int i = blockIdx.x * blockDim.x + threadIdx.x;
  if (i < n) {
    int b = i >> 10;
    int off = 0;
    for (int j = 0; j < b; ++j) off += bsum[j];  // <=48 iters, L2-cached
    rp[i] += off;
    cnt[i] = 0;
  }
  if (i == 0) {
    int tot = 0;
    for (int j = 0; j < nb; ++j) tot += bsum[j];
    rp[n] = tot;
  }
}

__global__ void scatter_k(const int* __restrict__ src, const int* __restrict__ dst,
                          const int* __restrict__ rp, int* __restrict__ cur,
                          int* __restrict__ out, int E) {
  int e = blockIdx.x * blockDim.x + threadIdx.x;
  if (e < E) {
    int d = dst[e];
    int p = rp[d] + atomicAdd(&cur[d], 1);
    out[p] = src[e];
  }
}

// ---------------- weight pre-split (merged W1+W2): fp32 -> [n][K] bf16 hi/lo ----------
__global__ void convW_k(const float* __restrict__ W1, unsigned short* __restrict__ Wh1,
                        unsigned short* __restrict__ Wl1,
                        const float* __restrict__ W2, unsigned short* __restrict__ Wh2,
                        unsigned short* __restrict__ Wl2) {
  int id = blockIdx.x * 256 + threadIdx.x;
  if (id < 256 * 512) {  // W1 [512,256] -> [256][512]
    int n = id >> 9, k = id & 511;
    unsigned h, l;
    split_bf16(W1[k * 256 + n], h, l);
    Wh1[id] = (unsigned short)h;
    Wl1[id] = (unsigned short)l;
  } else {               // W2 [256,160] -> padded [256][256]
    int id2 = id - 256 * 512;
    int n = id2 >> 8, k = id2 & 255;
    int hh = n >> 6, c = n & 63;
    float a = (c < OUTC) ? W2[k * 160 + hh * OUTC + c] : 0.f;
    unsigned h, l;
    split_bf16(a, h, l);
    Wh2[id2] = (unsigned short)h;
    Wl2[id2] = (unsigned short)l;
  }
}

// ---------------- DMA GEMM: C[M,256] = A[M,K] @ B[K,256] ----------
// R13: 40KB LDS -> 4 blocks/CU, ONE grid round (R12's 48KB yielded only ~2
// resident blocks by the occupancy math: 20% occ + 77us fit a 2-round
// execution of ~38us each; grid 782 <= 4*256 slots kills the second round).
//   A:    single buffer @0 (16KB), R12's proven lgkm+barrier overwrite protocol
//   B-hi: double buffer @16384 + (k&1)*8192 (full-iter prefetch distance)
//   B-lo: single buffer @32768 (8KB), same protocol as A
// Per-iter schedule:
//   DMA_Bhi(k+1) -> vmcnt(2) -> barrier1 -> ds_read A(k),Bhi(k),Blo(k)
//   -> lgkmcnt(0) -> barrier2 -> DMA_A(k+1)+DMA_Blo(k+1) -> 48 MFMA
// vmcnt audit (in-order, m135): steady state at the wait, queue =
// [Bhi(k)2(oldest), A(k)4, Blo(k)2, Bhi(k+1)2] -> vmcnt(2) drains exactly
// tile k, leaves Bhi(k+1). Last iter: vmcnt(0), no mid-iter issue.
// Overwrite safety: every wave drains its own ds_reads (lgkmcnt(0)) before
// barrier2; barrier2 release => all reads of A/Blo retired chip-wide before
// the DMA writes can land (proven by R12's unchanged absmax).
// Swizzle unchanged from R11 (write-side source permute + read-side XOR).
template <bool A_FP32, bool COMPACT>
__global__ __launch_bounds__(256, 4) void gemm_dma(const void* Aptr_h, const void* Aptr_l,
                                                   const unsigned short* __restrict__ Bh,
                                                   const unsigned short* __restrict__ Bl,
                                                   float* __restrict__ C, int M, int K) {
  // layout: A_FP32: Af [128][32] f32 @0 (16KB)
  //         !A_FP32: Ahs [128][32] bf16 @0 (8KB), Als @8192
  //         Bhi: @16384 + (k&1)*8192 ; Blo: @32768
  __shared__ __align__(16) unsigned char lds[40960];
  const int tid = threadIdx.x;
  const int lane = tid & 63;
  const int w = tid >> 6;
  const int wr = w >> 1, wc = w & 1;
  const int row0 = blockIdx.y * 128;
  const int col0 = blockIdx.x * 128;
  const int fr = lane & 15, fq = lane >> 4;
  // read-side swizzle terms; write-side source-chunk permutations
  const int swz8 = fr & 7;
  const int swz4 = (fr & 3) ^ ((fr >> 2) & 1);
  const int srcA8 = (lane & 7) ^ (lane >> 3);
  const int srcB4 = (lane & 3) ^ ((lane >> 2) & 3) ^ ((lane >> 4) & 1);

  floatx4 acc[4][4];
#pragma unroll
  for (int i = 0; i < 4; ++i)
#pragma unroll
    for (int j = 0; j < 4; ++j) acc[i][j] = (floatx4){0.f, 0.f, 0.f, 0.f};

  const float* Af32 = (const float*)Aptr_h;
  const unsigned short* Agh = (const unsigned short*)Aptr_h;
  const unsigned short* Agl = (const unsigned short*)Aptr_l;

  // 4 DMA insts per wave (A tile, single buffer @0)
#define DMA_A(K0)                                                                   \
  do {                                                                              \
    if (A_FP32) {                                                                   \
      _Pragma("unroll") for (int t = 0; t < 4; ++t) {                               \
        int arow = w * 32 + t * 8 + (lane >> 3);                                    \
        int gr = row0 + arow; gr = gr < M ? gr : M - 1;                             \
        dma16(&Af32[(size_t)gr * K + (K0) + srcA8 * 4],                             \
              lds + (size_t)(w * 32 + t * 8) * 128);                                \
      }                                                                             \
    } else {                                                                        \
      _Pragma("unroll") for (int t = 0; t < 2; ++t) {                               \
        int arow = w * 32 + t * 16 + (lane >> 2);                                   \
        int gr = row0 + arow; gr = gr < M ? gr : M - 1;                             \
        size_t go = (size_t)gr * K + (K0) + srcB4 * 8;                              \
        dma16(&Agh[go], lds + (size_t)(w * 32 + t * 16) * 64);                      \
        dma16(&Agl[go], lds + 8192 + (size_t)(w * 32 + t * 16) * 64);               \
      }                                                                             \
    }                                                                               \
  } while (0)

  // 2 DMA insts per wave (B-hi tile into dbuf at BASE)
#define DMA_BHI(K0, BASE)                                                           \
  do {                                                                              \
    _Pragma("unroll") for (int t = 0; t < 2; ++t) {                                 \
      int nrow = w * 32 + t * 16 + (lane >> 2);                                     \
      size_t go = (size_t)(col0 + nrow) * K + (K0) + srcB4 * 8;                     \
      dma16(&Bh[go], lds + (BASE) + (size_t)(w * 32 + t * 16) * 64);                \
    }                                                                               \
  } while (0)

  // 2 DMA insts per wave (B-lo tile, single buffer @32768)
#define DMA_BLO(K0)                                                                 \
  do {                                                                              \
    _Pragma("unroll") for (int t = 0; t < 2; ++t) {                                 \
      int nrow = w * 32 + t * 16 + (lane >> 2);                                     \
      size_t go = (size_t)(col0 + nrow) * K + (K0) + srcB4 * 8;                     \
      dma16(&Bl[go], lds + 32768 + (size_t)(w * 32 + t * 16) * 64);                 \
    }                                                                               \
  } while (0)

  const int nk = K >> 5;
  DMA_BHI(0, 16384);
  DMA_A(0);
  DMA_BLO(0);
  asm volatile("" ::: "memory");
  for (int k = 0; k < nk; ++k) {
    const int bbase = 16384 + ((k & 1) << 13);
    if (k + 1 < nk) {
      DMA_BHI((k + 1) << 5, 16384 + (((k + 1) & 1) << 13));
      asm volatile("s_waitcnt vmcnt(2)" ::: "memory");  // tile k done; Bhi(k+1) in flight
    } else {
      asm volatile("s_waitcnt vmcnt(0)" ::: "memory");
    }
    asm volatile("s_barrier" ::: "memory");  // tile k visible to all waves

    bf16x8 ah[4], al[4], bh[4], bl[4];
#pragma unroll
    for (int i = 0; i < 4; ++i) {
      int arow = wr * 64 + i * 16 + fr;
      if (A_FP32) {
        const unsigned char* pa = lds + (size_t)arow * 128;
        float4 v0 = *(const float4*)(pa + (((fq * 2) ^ swz8) * 16));
        float4 v1 = *(const float4*)(pa + (((fq * 2 + 1) ^ swz8) * 16));
        unsigned u0 = __float_as_uint(v0.x), u1 = __float_as_uint(v0.y);
        unsigned u2 = __float_as_uint(v0.z), u3 = __float_as_uint(v0.w);
        unsigned u4 = __float_as_uint(v1.x), u5 = __float_as_uint(v1.y);
        unsigned u6 = __float_as_uint(v1.z), u7 = __float_as_uint(v1.w);
        uint4 H;
        H.x = (u0 >> 16) | (u1 & 0xFFFF0000u);
        H.y = (u2 >> 16) | (u3 & 0xFFFF0000u);
        H.z = (u4 >> 16) | (u5 & 0xFFFF0000u);
        H.w = (u6 >> 16) | (u7 & 0xFFFF0000u);
        uint4 L;
        L.x = (__float_as_uint(v0.x - __uint_as_float(u0 & 0xFFFF0000u)) >> 16) |
              (__float_as_uint(v0.y - __uint_as_float(u1 & 0xFFFF0000u)) & 0xFFFF0000u);
        L.y = (__float_as_uint(v0.z - __uint_as_float(u2 & 0xFFFF0000u)) >> 16) |
              (__float_as_uint(v0.w - __uint_as_float(u3 & 0xFFFF0000u)) & 0xFFFF0000u);
        L.z = (__float_as_uint(v1.x - __uint_as_float(u4 & 0xFFFF0000u)) >> 16) |
              (__float_as_uint(v1.y - __uint_as_float(u5 & 0xFFFF0000u)) & 0xFFFF0000u);
        L.w = (__float_as_uint(v1.z - __uint_as_float(u6 & 0xFFFF0000u)) >> 16) |
              (__float_as_uint(v1.w - __uint_as_float(u7 & 0xFFFF0000u)) & 0xFFFF0000u);
        ah[i] = *(bf16x8*)&H;
        al[i] = *(bf16x8*)&L;
      } else {
        ah[i] = *(bf16x8*)(lds + (size_t)arow * 64 + ((fq ^ swz4) * 16));
        al[i] = *(bf16x8*)(lds + 8192 + (size_t)arow * 64 + ((fq ^ swz4) * 16));
      }
      int brow = wc * 64 + i * 16 + fr;
      bh[i] = *(bf16x8*)(lds + bbase + (size_t)brow * 64 + ((fq ^ swz4) * 16));
      bl[i] = *(bf16x8*)(lds + 32768 + (size_t)brow * 64 + ((fq ^ swz4) * 16));
    }
    asm volatile("s_waitcnt lgkmcnt(0)" ::: "memory");  // my reads retired
    asm volatile("s_barrier" ::: "memory");             // all reads retired -> A/Blo free
    if (k + 1 < nk) {                                   // overwrite for k+1
      DMA_A((k + 1) << 5);
      DMA_BLO((k + 1) << 5);
    }

#pragma unroll
    for (int i = 0; i < 4; ++i)
#pragma unroll
      for (int j = 0; j < 4; ++j) {
        acc[i][j] = __builtin_amdgcn_mfma_f32_16x16x32_bf16(ah[i], bh[j], acc[i][j], 0, 0, 0);
        acc[i][j] = __builtin_amdgcn_mfma_f32_16x16x32_bf16(ah[i], bl[j], acc[i][j], 0, 0, 0);
        acc[i][j] = __builtin_amdgcn_mfma_f32_16x16x32_bf16(al[i], bh[j], acc[i][j], 0, 0, 0);
      }
  }
#undef DMA_A
#undef DMA_BHI
#undef DMA_BLO

  // epilogue: C/D layout col=lane&15, row=(lane>>4)*4+r  [m89]
#pragma unroll
  for (int i = 0; i < 4; ++i) {
    int grow_base = row0 + wr * 64 + i * 16 + fq * 4;
#pragma unroll
    for (int r = 0; r < 4; ++r) {
      int grow = grow_base + r;
      if (grow < M) {
        if (COMPACT) {
          int head = blockIdx.x * 2 + wc;
#pragma unroll
          for (int j = 0; j < 4; ++j) {
            int cc = j * 16 + fr;
            if (cc < OUTC) C[(size_t)grow * 160 + head * OUTC + cc] = acc[i][j][r];
          }
        } else {
#pragma unroll
          for (int j = 0; j < 4; ++j)
            C[(size_t)grow * 256 + col0 + wc * 64 + j * 16 + fr] = acc[i][j][r];
        }
      }
    }
  }
}

// ---------------- layer-1 agg: wave per node; emits pre-split bf16 activations ----
// edge loop unrolled x4 (R12; throughput-bound at high TLP, left unchanged)
__global__ __launch_bounds__(256) void agg1_k(const float* __restrict__ h,
                                              const int* __restrict__ rp,
                                              const int* __restrict__ srt,
                                              const float* __restrict__ b1,
                                              unsigned short* __restrict__ outh,
                                              unsigned short* __restrict__ outl, int Nn) {
  int wv = threadIdx.x >> 6, lane = threadIdx.x & 63;
  int node = blockIdx.x * 4 + wv;
  if (node >= Nn) node = Nn - 1;
  const float4 xi = *(const float4*)&h[(size_t)node * 256 + lane * 4];
  float p = xi.x * xi.x + xi.y * xi.y + xi.z * xi.z + xi.w * xi.w;
  p += __shfl_xor(p, 1); p += __shfl_xor(p, 2); p += __shfl_xor(p, 4); p += __shfl_xor(p, 8);
  float a = p > 0.f ? p : NEG * p;      // self-loop logit
  float m = a, l = 1.f;
  float4 acc = xi;
  const int e0 = rp[node], e1 = rp[node + 1];
  int e = e0;
  for (; e + 4 <= e1; e += 4) {
    int s0 = srt[e], s1 = srt[e + 1], s2 = srt[e + 2], s3 = srt[e + 3];
    const float4 xj0 = *(const float4*)&h[(size_t)s0 * 256 + lane * 4];
    const float4 xj1 = *(const float4*)&h[(size_t)s1 * 256 + lane * 4];
    const float4 xj2 = *(const float4*)&h[(size_t)s2 * 256 + lane * 4];
    const float4 xj3 = *(const float4*)&h[(size_t)s3 * 256 + lane * 4];
    float q0 = xi.x * xj0.x + xi.y * xj0.y + xi.z * xj0.z + xi.w * xj0.w;
    float q1 = xi.x * xj1.x + xi.y * xj1.y + xi.z * xj1.z + xi.w * xj1.w;
    float q2 = xi.x * xj2.x + xi.y * xj2.y + xi.z * xj2.z + xi.w * xj2.w;
    float q3 = xi.x * xj3.x + xi.y * xj3.y + xi.z * xj3.z + xi.w * xj3.w;
    q0 += __shfl_xor(q0, 1); q1 += __shfl_xor(q1, 1); q2 += __shfl_xor(q2, 1); q3 += __shfl_xor(q3, 1);
    q0 += __shfl_xor(q0, 2); q1 += __shfl_xor(q1, 2); q2 += __shfl_xor(q2, 2); q3 += __shfl_xor(q3, 2);
    q0 += __shfl_xor(q0, 4); q1 += __shfl_xor(q1, 4); q2 += __shfl_xor(q2, 4); q3 += __shfl_xor(q3, 4);
    q0 += __shfl_xor(q0, 8); q1 += __shfl_xor(q1, 8); q2 += __shfl_xor(q2, 8); q3 += __shfl_xor(q3, 8);
    float a0 = q0 > 0.f ? q0 : NEG * q0;
    float a1 = q1 > 0.f ? q1 : NEG * q1;
    float a2 = q2 > 0.f ? q2 : NEG * q2;
    float a3 = q3 > 0.f ? q3 : NEG * q3;
    float nm = fmaxf(fmaxf(m, fmaxf(a0, a1)), fmaxf(a2, a3));
    float sc = __expf(m - nm);
    float w0 = __expf(a0 - nm), w1 = __expf(a1 - nm);
    float w2 = __expf(a2 - nm), w3 = __expf(a3 - nm);
    l = l * sc + w0 + w1 + w2 + w3;
    acc.x = acc.x * sc + w0 * xj0.x + w1 * xj1.x + w2 * xj2.x + w3 * xj3.x;
    acc.y = acc.y * sc + w0 * xj0.y + w1 * xj1.y + w2 * xj2.y + w3 * xj3.y;
    acc.z = acc.z * sc + w0 * xj0.z + w1 * xj1.z + w2 * xj2.z + w3 * xj3.z;
    acc.w = acc.w * sc + w0 * xj0.w + w1 * xj1.w + w2 * xj2.w + w3 * xj3.w;
    m = nm;
  }
  for (; e < e1; ++e) {
    int s = srt[e];
    const float4 xj = *(const float4*)&h[(size_t)s * 256 + lane * 4];
    float q = xi.x * xj.x + xi.y * xj.y + xi.z * xj.z + xi.w * xj.w;
    q += __shfl_xor(q, 1); q += __shfl_xor(q, 2); q += __shfl_xor(q, 4); q += __shfl_xor(q, 8);
    float al = q > 0.f ? q : NEG * q;
    float nm = fmaxf(m, al);
    float sc = __expf(m - nm), wt = __expf(al - nm);
    l = l * sc + wt;
    acc.x = acc.x * sc + wt * xj.x;
    acc.y = acc.y * sc + wt * xj.y;
    acc.z = acc.z * sc + wt * xj.z;
    acc.w = acc.w * sc + wt * xj.w;
    m = nm;
  }
  float inv = 1.f / (l + EPSV);
  const float4 bb = *(const float4*)&b1[lane * 4];
  float4 o;
  o.x = acc.x * inv + bb.x;
  o.y = acc.y * inv + bb.y;
  o.z = acc.z * inv + bb.z;
  o.w = acc.w * inv + bb.w;
  o.x = o.x > 0.f ? o.x : __expf(o.x) - 1.f;
  o.y = o.y > 0.f ? o.y : __expf(o.y) - 1.f;
  o.z = o.z > 0.f ? o.z : __expf(o.z) - 1.f;
  o.w = o.w > 0.f ? o.w : __expf(o.w) - 1.f;
  unsigned h0, l0, h1, l1, h2, l2, h3, l3;
  split_bf16(o.x, h0, l0);
  split_bf16(o.y, h1, l1);
  split_bf16(o.z, h2, l2);
  split_bf16(o.w, h3, l3);
  size_t base = (size_t)node * 256 + lane * 4;
  *(uint2*)&outh[base] = make_uint2(h0 | (h1 << 16), h2 | (h3 << 16));
  *(uint2*)&outl[base] = make_uint2(l0 | (l1 << 16), l2 | (l3 << 16));
}

// ---------------- layer-2 agg (compact [N,160] input) + head-mean + log_softmax ----------------
__global__ __launch_bounds__(256) void agg2_k(const float* __restrict__ h,
                                              const int* __restrict__ rp,
                                              const int* __restrict__ srt,
                                              const float* __restrict__ b2,
                                              float* __restrict__ out, int Nn) {
  __shared__ float buf[4][160];
  int wv = threadIdx.x >> 6, lane = threadIdx.x & 63;
  int node = blockIdx.x * 4 + wv;
  if (node >= Nn) node = Nn - 1;
  const int head = lane >> 4, c4 = lane & 15;
  const bool act = c4 < 10;  // 10 lanes x float4 = 40 channels per head
  float4 xi = make_float4(0.f, 0.f, 0.f, 0.f);
  if (act) xi = *(const float4*)&h[(size_t)node * 160 + head * OUTC + c4 * 4];
  float p = xi.x * xi.x + xi.y * xi.y + xi.z * xi.z + xi.w * xi.w;
  p += __shfl_xor(p, 1); p += __shfl_xor(p, 2); p += __shfl_xor(p, 4); p += __shfl_xor(p, 8);
  float a = p > 0.f ? p : NEG * p;
  float m = a, l = 1.f;
  float4 acc = xi;
  const int e0 = rp[node], e1 = rp[node + 1];
  int e = e0;
  for (; e + 4 <= e1; e += 4) {
    int s0 = srt[e], s1 = srt[e + 1], s2 = srt[e + 2], s3 = srt[e + 3];
    float4 xj0 = make_float4(0.f, 0.f, 0.f, 0.f);
    float4 xj1 = make_float4(0.f, 0.f, 0.f, 0.f);
    float4 xj2 = make_float4(0.f, 0.f, 0.f, 0.f);
    float4 xj3 = make_float4(0.f, 0.f, 0.f, 0.f);
    if (act) {
      xj0 = *(const float4*)&h[(size_t)s0 * 160 + head * OUTC + c4 * 4];
      xj1 = *(const float4*)&h[(size_t)s1 * 160 + head * OUTC + c4 * 4];
      xj2 = *(const float4*)&h[(size_t)s2 * 160 + head * OUTC + c4 * 4];
      xj3 = *(const float4*)&h[(size_t)s3 * 160 + head * OUTC + c4 * 4];
    }
    float q0 = xi.x * xj0.x + xi.y * xj0.y + xi.z * xj0.z + xi.w * xj0.w;
    float q1 = xi.x * xj1.x + xi.y * xj1.y + xi.z * xj1.z + xi.w * xj1.w;
    float q2 = xi.x * xj2.x + xi.y * xj2.y + xi.z * xj2.z + xi.w * xj2.w;
    float q3 = xi.x * xj3.x + xi.y * xj3.y + xi.z * xj3.z + xi.w * xj3.w;
    q0 += __shfl_xor(q0, 1); q1 += __shfl_xor(q1, 1); q2 += __shfl_xor(q2, 1); q3 += __shfl_xor(q3, 1);
    q0 += __shfl_xor(q0, 2); q1 += __shfl_xor(q1, 2); q2 += __shfl_xor(q2, 2); q3 += __shfl_xor(q3, 2);
    q0 += __shfl_xor(q0, 4); q1 += __shfl_xor(q1, 4); q2 += __shfl_xor(q2, 4); q3 += __shfl_xor(q3, 4);
    q0 += __shfl_xor(q0, 8); q1 += __shfl_xor(q1, 8); q2 += __shfl_xor(q2, 8); q3 += __shfl_xor(q3, 8);
    float a0 = q0 > 0.f ? q0 : NEG * q0;
    float a1 = q1 > 0.f ? q1 : NEG * q1;
    float a2 = q2 > 0.f ? q2 : NEG * q2;
    float a3 = q3 > 0.f ? q3 : NEG * q3;
    float nm = fmaxf(fmaxf(m, fmaxf(a0, a1)), fmaxf(a2, a3));
    float sc = __expf(m - nm);
    float w0 = __expf(a0 - nm), w1 = __expf(a1 - nm);
    float w2 = __expf(a2 - nm), w3 = __expf(a3 - nm);
    l = l * sc + w0 + w1 + w2 + w3;
    acc.x = acc.x * sc + w0 * xj0.x + w1 * xj1.x + w2 * xj2.x + w3 * xj3.x;
    acc.y = acc.y * sc + w0 * xj0.y + w1 * xj1.y + w2 * xj2.y + w3 * xj3.y;
    acc.z = acc.z * sc + w0 * xj0.z + w1 * xj1.z + w2 * xj2.z + w3 * xj3.z;
    acc.w = acc.w * sc + w0 * xj0.w + w1 * xj1.w + w2 * xj2.w + w3 * xj3.w;
    m = nm;
  }
  for (; e < e1; ++e) {
    int s = srt[e];
    float4 xj = make_float4(0.f, 0.f, 0.f, 0.f);
    if (act) xj = *(const float4*)&h[(size_t)s * 160 + head * OUTC + c4 * 4];
    float q = xi.x * xj.x + xi.y * xj.y + xi.z * xj.z + xi.w * xj.w;
    q += __shfl_xor(q, 1); q += __shfl_xor(q, 2); q += __shfl_xor(q, 4); q += __shfl_xor(q, 8);
    float al = q > 0.f ? q : NEG * q;
    float nm = fmaxf(m, al);
    float sc = __expf(m - nm), wt = __expf(al - nm);
    l = l * sc + wt;
    acc.x = acc.x * sc + wt * xj.x;
    acc.y = acc.y * sc + wt * xj.y;
    acc.z = acc.z * sc + wt * xj.z;
    acc.w = acc.w * sc + wt * xj.w;
    m = nm;
  }
  float inv = 1.f / (l + EPSV);
  if (act) {
    float4 res;
    res.x = acc.x * inv; res.y = acc.y * inv; res.z = acc.z * inv; res.w = acc.w * inv;
    *(float4*)&buf[wv][head * OUTC + c4 * 4] = res;
  }
  __syncthreads();
  const bool valid = lane < OUTC;
  float v = 0.f;
  if (valid)
    v = 0.25f * (buf[wv][lane] + buf[wv][OUTC + lane] + buf[wv][2 * OUTC + lane] +
                 buf[wv][3 * OUTC + lane]) + b2[lane];
  float t = valid ? v : -1e30f;
#pragma unroll
  for (int off = 32; off; off >>= 1) t = fmaxf(t, __shfl_xor(t, off));
  float ex = valid ? __expf(v - t) : 0.f;
  float s = ex;
#pragma unroll
  for (int off = 32; off; off >>= 1) s += __shfl_xor(s, off);
  float lse = t + __logf(s);
  if (valid) out[(size_t)node * OUTC + lane] = v - lse;
  if (blockIdx.x == 0 && threadIdx.x == 0) out[(size_t)Nn * OUTC] = 0.f;  // att_loss
}

extern "C" void kernel_launch(void* const* d_in, const int* in_sizes, int n_in,
                              void* d_out, int out_size, void* d_ws, size_t ws_size,
                              hipStream_t stream) {
  const float* x  = (const float*)d_in[0];
  const int*   ei = (const int*)d_in[1];
  const float* W1 = (const float*)d_in[2];
  const float* b1 = (const float*)d_in[3];
  const float* W2 = (const float*)d_in[4];
  const float* b2 = (const float*)d_in[5];
  float* out = (float*)d_out;

  const int Nn = in_sizes[0] / 512;  // 50000
  const int E  = in_sizes[1] / 2;    // 400000
  const int* esrc = ei;
  const int* edst = ei + E;
  const int NB = (Nn + 1023) / 1024;

  // workspace layout
  char* ws = (char*)d_ws;
  const size_t szH = (size_t)Nn * 256 * sizeof(float);  // 51.2 MB
  float* h1 = (float*)(ws);           // GEMM1 out [N,256] f32; reused as h2 [N,160] f32
  size_t off = szH;
  unsigned short* g1h = (unsigned short*)(ws + off); off += (size_t)Nn * 256 * 2;  // 25.6MB
  unsigned short* g1l = (unsigned short*)(ws + off); off += (size_t)Nn * 256 * 2;
  int* rp = (int*)(ws + off);   off += ((size_t)(Nn + 1) * 4 + 15) & ~(size_t)15;
  int* cnt = (int*)(ws + off);  off += ((size_t)Nn * 4 + 15) & ~(size_t)15;
  int* srt = (int*)(ws + off);  off += ((size_t)E * 4 + 15) & ~(size_t)15;
  int* bsum = (int*)(ws + off); off += 1024;
  unsigned short* Wh1 = (unsigned short*)(ws + off); off += (size_t)256 * 512 * 2;
  unsigned short* Wl1 = (unsigned short*)(ws + off); off += (size_t)256 * 512 * 2;
  unsigned short* Wh2 = (unsigned short*)(ws + off); off += (size_t)256 * 256 * 2;
  unsigned short* Wl2 = (unsigned short*)(ws + off); off += (size_t)256 * 256 * 2;
  float* h2 = h1;

  // CSR by destination (scanC zeroes cnt for scatter's cursor -- one less memset)
  hipMemsetAsync(cnt, 0, (size_t)Nn * sizeof(int), stream);
  hist_k<<<(E + 255) / 256, 256, 0, stream>>>(edst, cnt, E);
  scanA_k<<<NB, 1024, 0, stream>>>(cnt, rp, bsum, Nn);
  scanC_k<<<(Nn + 255) / 256, 256, 0, stream>>>(rp, bsum, cnt, Nn, NB);
  scatter_k<<<(E + 255) / 256, 256, 0, stream>>>(esrc, edst, rp, cnt, srt, E);

  // weight pre-split (merged)
  convW_k<<<768, 256, 0, stream>>>(W1, Wh1, Wl1, W2, Wh2, Wl2);

  // layer 1: A = x fp32 (read-time split), B = Wh1/Wl1
  gemm_dma<true, false>
      <<<dim3(2, (Nn + 127) / 128), 256, 0, stream>>>(x, nullptr, Wh1, Wl1, h1, Nn, 512);
  agg1_k<<<(Nn + 3) / 4, 256, 0, stream>>>(h1, rp, srt, b1, g1h, g1l, Nn);

  // layer 2: A = g1 pre-split bf16, compact [N,160] output
  gemm_dma<false, true>
      <<<dim3(2, (Nn + 127) / 128), 256, 0, stream>>>(g1h, g1l, Wh2, Wl2, h2, Nn, 256);
  agg2_k<<<(Nn + 3) / 4, 256, 0, stream>>>(h2, rp, srt, b2, out, Nn);
}

// Round 6
// 390.734 us; speedup vs baseline: 1.4904x; 1.4904x over previous
//
#include <hip/hip_runtime.h>
#include <cstddef>
#include <cstdint>

#define HEADS 4
#define OUTC  40
#define NEG   0.2f
#define EPSV  1e-16f

typedef __bf16 bf16x8 __attribute__((ext_vector_type(8)));
typedef float  floatx4 __attribute__((ext_vector_type(4)));

__device__ __forceinline__ void split_bf16(float a, unsigned& hi, unsigned& lo) {
  unsigned u = __float_as_uint(a);
  hi = u >> 16;                                   // RTZ high bf16
  float hf = __uint_as_float(u & 0xFFFF0000u);
  lo = __float_as_uint(a - hf) >> 16;             // RTZ residual bf16
}

// async global->LDS DMA, 16B per lane. lds ptr must be wave-uniform base;
// HW writes lane i at base + i*16 (m97/m104).
__device__ __forceinline__ void dma16(const void* g, void* l) {
  __builtin_amdgcn_global_load_lds(
      (const __attribute__((address_space(1))) unsigned int*)g,
      (__attribute__((address_space(3))) unsigned int*)l, 16, 0, 0);
}

// ---------------- CSR build ----------------
__global__ void hist_k(const int* __restrict__ dst, int* __restrict__ cnt, int E) {
  int e = blockIdx.x * blockDim.x + threadIdx.x;
  if (e < E) atomicAdd(&cnt[dst[e]], 1);
}

__global__ __launch_bounds__(1024) void scanA_k(const int* __restrict__ cnt,
                                                int* __restrict__ rp,
                                                int* __restrict__ bsum, int n) {
  __shared__ int sh[1024];
  int i = blockIdx.x * 1024 + threadIdx.x;
  int v = (i < n) ? cnt[i] : 0;
  sh[threadIdx.x] = v;
  __syncthreads();
  for (int d = 1; d < 1024; d <<= 1) {
    int t = (threadIdx.x >= d) ? sh[threadIdx.x - d] : 0;
    __syncthreads();
    sh[threadIdx.x] += t;
    __syncthreads();
  }
  if (i < n) rp[i] = sh[threadIdx.x] - v;  // block-local exclusive
  if (threadIdx.x == 1023) bsum[blockIdx.x] = sh[1023];
}

// adds bsum prefix to rp (folds old scanB); rp[n] = total.
// Also zeroes cnt (used as scatter cursor) -- saves a memset launch.
__global__ void scanC_k(int* __restrict__ rp, const int* __restrict__ bsum,
                        int* __restrict__ cnt, int n, int nb) {
  int i = blockIdx.x * blockDim.x + threadIdx.x;
  if (i < n) {
    int b = i >> 10;
    int off = 0;
    for (int j = 0; j < b; ++j) off += bsum[j];  // <=48 iters, L2-cached
    rp[i] += off;
    cnt[i] = 0;
  }
  if (i == 0) {
    int tot = 0;
    for (int j = 0; j < nb; ++j) tot += bsum[j];
    rp[n] = tot;
  }
}

__global__ void scatter_k(const int* __restrict__ src, const int* __restrict__ dst,
                          const int* __restrict__ rp, int* __restrict__ cur,
                          int* __restrict__ out, int E) {
  int e = blockIdx.x * blockDim.x + threadIdx.x;
  if (e < E) {
    int d = dst[e];
    int p = rp[d] + atomicAdd(&cur[d], 1);
    out[p] = src[e];
  }
}

// ---------------- weight pre-split (merged W1+W2): fp32 -> [n][K] bf16 hi/lo ----------
__global__ void convW_k(const float* __restrict__ W1, unsigned short* __restrict__ Wh1,
                        unsigned short* __restrict__ Wl1,
                        const float* __restrict__ W2, unsigned short* __restrict__ Wh2,
                        unsigned short* __restrict__ Wl2) {
  int id = blockIdx.x * 256 + threadIdx.x;
  if (id < 256 * 512) {  // W1 [512,256] -> [256][512]
    int n = id >> 9, k = id & 511;
    unsigned h, l;
    split_bf16(W1[k * 256 + n], h, l);
    Wh1[id] = (unsigned short)h;
    Wl1[id] = (unsigned short)l;
  } else {               // W2 [256,160] -> padded [256][256]
    int id2 = id - 256 * 512;
    int n = id2 >> 8, k = id2 & 255;
    int hh = n >> 6, c = n & 63;
    float a = (c < OUTC) ? W2[k * 160 + hh * OUTC + c] : 0.f;
    unsigned h, l;
    split_bf16(a, h, l);
    Wh2[id2] = (unsigned short)h;
    Wl2[id2] = (unsigned short)l;
  }
}

// ---------------- DMA GEMM: C[M,256] = A[M,K] @ B[K,256] ----------
// R14 = R13's 40KB layout + launch_bounds back to (256,3).
// R13 post-mortem: __launch_bounds__(256,4) capped the allocator (chose 64
// VGPR < ~110 live) -> accumulator spilled to scratch (WRITE_SIZE 50->410MB,
// dur 77->254us). The 40KB layout itself DID raise residency (occ 30%, hbm
// 2.7TB/s even while spilling). At VGPR~84-88 the HW cap is 5 waves/SIMD, so
// 4 blocks/CU still fit at runtime (LDS limit 160/40 = 4) without the
// compiler constraint.
//   A:    single buffer @0 (16KB), lgkm+barrier overwrite protocol (R12-proven)
//   B-hi: double buffer @16384 + (k&1)*8192 (full-iter prefetch distance)
//   B-lo: single buffer @32768 (8KB), same protocol as A
// Per-iter schedule:
//   DMA_Bhi(k+1) -> vmcnt(2) -> barrier1 -> ds_read A(k),Bhi(k),Blo(k)
//   -> lgkmcnt(0) -> barrier2 -> DMA_A(k+1)+DMA_Blo(k+1) -> 48 MFMA
// vmcnt audit (in-order, m135): steady state at the wait, queue =
// [Bhi(k)2(oldest), A(k)4, Blo(k)2, Bhi(k+1)2] -> vmcnt(2) drains exactly
// tile k, leaves Bhi(k+1). Last iter: vmcnt(0), no mid-iter issue.
// Swizzle unchanged from R11 (write-side source permute + read-side XOR).
template <bool A_FP32, bool COMPACT>
__global__ __launch_bounds__(256, 3) void gemm_dma(const void* Aptr_h, const void* Aptr_l,
                                                   const unsigned short* __restrict__ Bh,
                                                   const unsigned short* __restrict__ Bl,
                                                   float* __restrict__ C, int M, int K) {
  // layout: A_FP32: Af [128][32] f32 @0 (16KB)
  //         !A_FP32: Ahs [128][32] bf16 @0 (8KB), Als @8192
  //         Bhi: @16384 + (k&1)*8192 ; Blo: @32768
  __shared__ __align__(16) unsigned char lds[40960];
  const int tid = threadIdx.x;
  const int lane = tid & 63;
  const int w = tid >> 6;
  const int wr = w >> 1, wc = w & 1;
  const int row0 = blockIdx.y * 128;
  const int col0 = blockIdx.x * 128;
  const int fr = lane & 15, fq = lane >> 4;
  // read-side swizzle terms; write-side source-chunk permutations
  const int swz8 = fr & 7;
  const int swz4 = (fr & 3) ^ ((fr >> 2) & 1);
  const int srcA8 = (lane & 7) ^ (lane >> 3);
  const int srcB4 = (lane & 3) ^ ((lane >> 2) & 3) ^ ((lane >> 4) & 1);

  floatx4 acc[4][4];
#pragma unroll
  for (int i = 0; i < 4; ++i)
#pragma unroll
    for (int j = 0; j < 4; ++j) acc[i][j] = (floatx4){0.f, 0.f, 0.f, 0.f};

  const float* Af32 = (const float*)Aptr_h;
  const unsigned short* Agh = (const unsigned short*)Aptr_h;
  const unsigned short* Agl = (const unsigned short*)Aptr_l;

  // 4 DMA insts per wave (A tile, single buffer @0)
#define DMA_A(K0)                                                                   \
  do {                                                                              \
    if (A_FP32) {                                                                   \
      _Pragma("unroll") for (int t = 0; t < 4; ++t) {                               \
        int arow = w * 32 + t * 8 + (lane >> 3);                                    \
        int gr = row0 + arow; gr = gr < M ? gr : M - 1;                             \
        dma16(&Af32[(size_t)gr * K + (K0) + srcA8 * 4],                             \
              lds + (size_t)(w * 32 + t * 8) * 128);                                \
      }                                                                             \
    } else {                                                                        \
      _Pragma("unroll") for (int t = 0; t < 2; ++t) {                               \
        int arow = w * 32 + t * 16 + (lane >> 2);                                   \
        int gr = row0 + arow; gr = gr < M ? gr : M - 1;                             \
        size_t go = (size_t)gr * K + (K0) + srcB4 * 8;                              \
        dma16(&Agh[go], lds + (size_t)(w * 32 + t * 16) * 64);                      \
        dma16(&Agl[go], lds + 8192 + (size_t)(w * 32 + t * 16) * 64);               \
      }                                                                             \
    }                                                                               \
  } while (0)

  // 2 DMA insts per wave (B-hi tile into dbuf at BASE)
#define DMA_BHI(K0, BASE)                                                           \
  do {                                                                              \
    _Pragma("unroll") for (int t = 0; t < 2; ++t) {                                 \
      int nrow = w * 32 + t * 16 + (lane >> 2);                                     \
      size_t go = (size_t)(col0 + nrow) * K + (K0) + srcB4 * 8;                     \
      dma16(&Bh[go], lds + (BASE) + (size_t)(w * 32 + t * 16) * 64);                \
    }                                                                               \
  } while (0)

  // 2 DMA insts per wave (B-lo tile, single buffer @32768)
#define DMA_BLO(K0)                                                                 \
  do {                                                                              \
    _Pragma("unroll") for (int t = 0; t < 2; ++t) {                                 \
      int nrow = w * 32 + t * 16 + (lane >> 2);                                     \
      size_t go = (size_t)(col0 + nrow) * K + (K0) + srcB4 * 8;                     \
      dma16(&Bl[go], lds + 32768 + (size_t)(w * 32 + t * 16) * 64);                 \
    }                                                                               \
  } while (0)

  const int nk = K >> 5;
  DMA_BHI(0, 16384);
  DMA_A(0);
  DMA_BLO(0);
  asm volatile("" ::: "memory");
  for (int k = 0; k < nk; ++k) {
    const int bbase = 16384 + ((k & 1) << 13);
    if (k + 1 < nk) {
      DMA_BHI((k + 1) << 5, 16384 + (((k + 1) & 1) << 13));
      asm volatile("s_waitcnt vmcnt(2)" ::: "memory");  // tile k done; Bhi(k+1) in flight
    } else {
      asm volatile("s_waitcnt vmcnt(0)" ::: "memory");
    }
    asm volatile("s_barrier" ::: "memory");  // tile k visible to all waves

    bf16x8 ah[4], al[4], bh[4], bl[4];
#pragma unroll
    for (int i = 0; i < 4; ++i) {
      int arow = wr * 64 + i * 16 + fr;
      if (A_FP32) {
        const unsigned char* pa = lds + (size_t)arow * 128;
        float4 v0 = *(const float4*)(pa + (((fq * 2) ^ swz8) * 16));
        float4 v1 = *(const float4*)(pa + (((fq * 2 + 1) ^ swz8) * 16));
        unsigned u0 = __float_as_uint(v0.x), u1 = __float_as_uint(v0.y);
        unsigned u2 = __float_as_uint(v0.z), u3 = __float_as_uint(v0.w);
        unsigned u4 = __float_as_uint(v1.x), u5 = __float_as_uint(v1.y);
        unsigned u6 = __float_as_uint(v1.z), u7 = __float_as_uint(v1.w);
        uint4 H;
        H.x = (u0 >> 16) | (u1 & 0xFFFF0000u);
        H.y = (u2 >> 16) | (u3 & 0xFFFF0000u);
        H.z = (u4 >> 16) | (u5 & 0xFFFF0000u);
        H.w = (u6 >> 16) | (u7 & 0xFFFF0000u);
        uint4 L;
        L.x = (__float_as_uint(v0.x - __uint_as_float(u0 & 0xFFFF0000u)) >> 16) |
              (__float_as_uint(v0.y - __uint_as_float(u1 & 0xFFFF0000u)) & 0xFFFF0000u);
        L.y = (__float_as_uint(v0.z - __uint_as_float(u2 & 0xFFFF0000u)) >> 16) |
              (__float_as_uint(v0.w - __uint_as_float(u3 & 0xFFFF0000u)) & 0xFFFF0000u);
        L.z = (__float_as_uint(v1.x - __uint_as_float(u4 & 0xFFFF0000u)) >> 16) |
              (__float_as_uint(v1.y - __uint_as_float(u5 & 0xFFFF0000u)) & 0xFFFF0000u);
        L.w = (__float_as_uint(v1.z - __uint_as_float(u6 & 0xFFFF0000u)) >> 16) |
              (__float_as_uint(v1.w - __uint_as_float(u7 & 0xFFFF0000u)) & 0xFFFF0000u);
        ah[i] = *(bf16x8*)&H;
        al[i] = *(bf16x8*)&L;
      } else {
        ah[i] = *(bf16x8*)(lds + (size_t)arow * 64 + ((fq ^ swz4) * 16));
        al[i] = *(bf16x8*)(lds + 8192 + (size_t)arow * 64 + ((fq ^ swz4) * 16));
      }
      int brow = wc * 64 + i * 16 + fr;
      bh[i] = *(bf16x8*)(lds + bbase + (size_t)brow * 64 + ((fq ^ swz4) * 16));
      bl[i] = *(bf16x8*)(lds + 32768 + (size_t)brow * 64 + ((fq ^ swz4) * 16));
    }
    asm volatile("s_waitcnt lgkmcnt(0)" ::: "memory");  // my reads retired
    asm volatile("s_barrier" ::: "memory");             // all reads retired -> A/Blo free
    if (k + 1 < nk) {                                   // overwrite for k+1
      DMA_A((k + 1) << 5);
      DMA_BLO((k + 1) << 5);
    }

#pragma unroll
    for (int i = 0; i < 4; ++i)
#pragma unroll
      for (int j = 0; j < 4; ++j) {
        acc[i][j] = __builtin_amdgcn_mfma_f32_16x16x32_bf16(ah[i], bh[j], acc[i][j], 0, 0, 0);
        acc[i][j] = __builtin_amdgcn_mfma_f32_16x16x32_bf16(ah[i], bl[j], acc[i][j], 0, 0, 0);
        acc[i][j] = __builtin_amdgcn_mfma_f32_16x16x32_bf16(al[i], bh[j], acc[i][j], 0, 0, 0);
      }
  }
#undef DMA_A
#undef DMA_BHI
#undef DMA_BLO

  // epilogue: C/D layout col=lane&15, row=(lane>>4)*4+r  [m89]
#pragma unroll
  for (int i = 0; i < 4; ++i) {
    int grow_base = row0 + wr * 64 + i * 16 + fq * 4;
#pragma unroll
    for (int r = 0; r < 4; ++r) {
      int grow = grow_base + r;
      if (grow < M) {
        if (COMPACT) {
          int head = blockIdx.x * 2 + wc;
#pragma unroll
          for (int j = 0; j < 4; ++j) {
            int cc = j * 16 + fr;
            if (cc < OUTC) C[(size_t)grow * 160 + head * OUTC + cc] = acc[i][j][r];
          }
        } else {
#pragma unroll
          for (int j = 0; j < 4; ++j)
            C[(size_t)grow * 256 + col0 + wc * 64 + j * 16 + fr] = acc[i][j][r];
        }
      }
    }
  }
}

// ---------------- layer-1 agg: wave per node; emits pre-split bf16 activations ----
// edge loop unrolled x4 (R12; throughput-bound at high TLP, left unchanged)
__global__ __launch_bounds__(256) void agg1_k(const float* __restrict__ h,
                                              const int* __restrict__ rp,
                                              const int* __restrict__ srt,
                                              const float* __restrict__ b1,
                                              unsigned short* __restrict__ outh,
                                              unsigned short* __restrict__ outl, int Nn) {
  int wv = threadIdx.x >> 6, lane = threadIdx.x & 63;
  int node = blockIdx.x * 4 + wv;
  if (node >= Nn) node = Nn - 1;
  const float4 xi = *(const float4*)&h[(size_t)node * 256 + lane * 4];
  float p = xi.x * xi.x + xi.y * xi.y + xi.z * xi.z + xi.w * xi.w;
  p += __shfl_xor(p, 1); p += __shfl_xor(p, 2); p += __shfl_xor(p, 4); p += __shfl_xor(p, 8);
  float a = p > 0.f ? p : NEG * p;      // self-loop logit
  float m = a, l = 1.f;
  float4 acc = xi;
  const int e0 = rp[node], e1 = rp[node + 1];
  int e = e0;
  for (; e + 4 <= e1; e += 4) {
    int s0 = srt[e], s1 = srt[e + 1], s2 = srt[e + 2], s3 = srt[e + 3];
    const float4 xj0 = *(const float4*)&h[(size_t)s0 * 256 + lane * 4];
    const float4 xj1 = *(const float4*)&h[(size_t)s1 * 256 + lane * 4];
    const float4 xj2 = *(const float4*)&h[(size_t)s2 * 256 + lane * 4];
    const float4 xj3 = *(const float4*)&h[(size_t)s3 * 256 + lane * 4];
    float q0 = xi.x * xj0.x + xi.y * xj0.y + xi.z * xj0.z + xi.w * xj0.w;
    float q1 = xi.x * xj1.x + xi.y * xj1.y + xi.z * xj1.z + xi.w * xj1.w;
    float q2 = xi.x * xj2.x + xi.y * xj2.y + xi.z * xj2.z + xi.w * xj2.w;
    float q3 = xi.x * xj3.x + xi.y * xj3.y + xi.z * xj3.z + xi.w * xj3.w;
    q0 += __shfl_xor(q0, 1); q1 += __shfl_xor(q1, 1); q2 += __shfl_xor(q2, 1); q3 += __shfl_xor(q3, 1);
    q0 += __shfl_xor(q0, 2); q1 += __shfl_xor(q1, 2); q2 += __shfl_xor(q2, 2); q3 += __shfl_xor(q3, 2);
    q0 += __shfl_xor(q0, 4); q1 += __shfl_xor(q1, 4); q2 += __shfl_xor(q2, 4); q3 += __shfl_xor(q3, 4);
    q0 += __shfl_xor(q0, 8); q1 += __shfl_xor(q1, 8); q2 += __shfl_xor(q2, 8); q3 += __shfl_xor(q3, 8);
    float a0 = q0 > 0.f ? q0 : NEG * q0;
    float a1 = q1 > 0.f ? q1 : NEG * q1;
    float a2 = q2 > 0.f ? q2 : NEG * q2;
    float a3 = q3 > 0.f ? q3 : NEG * q3;
    float nm = fmaxf(fmaxf(m, fmaxf(a0, a1)), fmaxf(a2, a3));
    float sc = __expf(m - nm);
    float w0 = __expf(a0 - nm), w1 = __expf(a1 - nm);
    float w2 = __expf(a2 - nm), w3 = __expf(a3 - nm);
    l = l * sc + w0 + w1 + w2 + w3;
    acc.x = acc.x * sc + w0 * xj0.x + w1 * xj1.x + w2 * xj2.x + w3 * xj3.x;
    acc.y = acc.y * sc + w0 * xj0.y + w1 * xj1.y + w2 * xj2.y + w3 * xj3.y;
    acc.z = acc.z * sc + w0 * xj0.z + w1 * xj1.z + w2 * xj2.z + w3 * xj3.z;
    acc.w = acc.w * sc + w0 * xj0.w + w1 * xj1.w + w2 * xj2.w + w3 * xj3.w;
    m = nm;
  }
  for (; e < e1; ++e) {
    int s = srt[e];
    const float4 xj = *(const float4*)&h[(size_t)s * 256 + lane * 4];
    float q = xi.x * xj.x + xi.y * xj.y + xi.z * xj.z + xi.w * xj.w;
    q += __shfl_xor(q, 1); q += __shfl_xor(q, 2); q += __shfl_xor(q, 4); q += __shfl_xor(q, 8);
    float al = q > 0.f ? q : NEG * q;
    float nm = fmaxf(m, al);
    float sc = __expf(m - nm), wt = __expf(al - nm);
    l = l * sc + wt;
    acc.x = acc.x * sc + wt * xj.x;
    acc.y = acc.y * sc + wt * xj.y;
    acc.z = acc.z * sc + wt * xj.z;
    acc.w = acc.w * sc + wt * xj.w;
    m = nm;
  }
  float inv = 1.f / (l + EPSV);
  const float4 bb = *(const float4*)&b1[lane * 4];
  float4 o;
  o.x = acc.x * inv + bb.x;
  o.y = acc.y * inv + bb.y;
  o.z = acc.z * inv + bb.z;
  o.w = acc.w * inv + bb.w;
  o.x = o.x > 0.f ? o.x : __expf(o.x) - 1.f;
  o.y = o.y > 0.f ? o.y : __expf(o.y) - 1.f;
  o.z = o.z > 0.f ? o.z : __expf(o.z) - 1.f;
  o.w = o.w > 0.f ? o.w : __expf(o.w) - 1.f;
  unsigned h0, l0, h1, l1, h2, l2, h3, l3;
  split_bf16(o.x, h0, l0);
  split_bf16(o.y, h1, l1);
  split_bf16(o.z, h2, l2);
  split_bf16(o.w, h3, l3);
  size_t base = (size_t)node * 256 + lane * 4;
  *(uint2*)&outh[base] = make_uint2(h0 | (h1 << 16), h2 | (h3 << 16));
  *(uint2*)&outl[base] = make_uint2(l0 | (l1 << 16), l2 | (l3 << 16));
}

// ---------------- layer-2 agg (compact [N,160] input) + head-mean + log_softmax ----------------
__global__ __launch_bounds__(256) void agg2_k(const float* __restrict__ h,
                                              const int* __restrict__ rp,
                                              const int* __restrict__ srt,
                                              const float* __restrict__ b2,
                                              float* __restrict__ out, int Nn) {
  __shared__ float buf[4][160];
  int wv = threadIdx.x >> 6, lane = threadIdx.x & 63;
  int node = blockIdx.x * 4 + wv;
  if (node >= Nn) node = Nn - 1;
  const int head = lane >> 4, c4 = lane & 15;
  const bool act = c4 < 10;  // 10 lanes x float4 = 40 channels per head
  float4 xi = make_float4(0.f, 0.f, 0.f, 0.f);
  if (act) xi = *(const float4*)&h[(size_t)node * 160 + head * OUTC + c4 * 4];
  float p = xi.x * xi.x + xi.y * xi.y + xi.z * xi.z + xi.w * xi.w;
  p += __shfl_xor(p, 1); p += __shfl_xor(p, 2); p += __shfl_xor(p, 4); p += __shfl_xor(p, 8);
  float a = p > 0.f ? p : NEG * p;
  float m = a, l = 1.f;
  float4 acc = xi;
  const int e0 = rp[node], e1 = rp[node + 1];
  int e = e0;
  for (; e + 4 <= e1; e += 4) {
    int s0 = srt[e], s1 = srt[e + 1], s2 = srt[e + 2], s3 = srt[e + 3];
    float4 xj0 = make_float4(0.f, 0.f, 0.f, 0.f);
    float4 xj1 = make_float4(0.f, 0.f, 0.f, 0.f);
    float4 xj2 = make_float4(0.f, 0.f, 0.f, 0.f);
    float4 xj3 = make_float4(0.f, 0.f, 0.f, 0.f);
    if (act) {
      xj0 = *(const float4*)&h[(size_t)s0 * 160 + head * OUTC + c4 * 4];
      xj1 = *(const float4*)&h[(size_t)s1 * 160 + head * OUTC + c4 * 4];
      xj2 = *(const float4*)&h[(size_t)s2 * 160 + head * OUTC + c4 * 4];
      xj3 = *(const float4*)&h[(size_t)s3 * 160 + head * OUTC + c4 * 4];
    }
    float q0 = xi.x * xj0.x + xi.y * xj0.y + xi.z * xj0.z + xi.w * xj0.w;
    float q1 = xi.x * xj1.x + xi.y * xj1.y + xi.z * xj1.z + xi.w * xj1.w;
    float q2 = xi.x * xj2.x + xi.y * xj2.y + xi.z * xj2.z + xi.w * xj2.w;
    float q3 = xi.x * xj3.x + xi.y * xj3.y + xi.z * xj3.z + xi.w * xj3.w;
    q0 += __shfl_xor(q0, 1); q1 += __shfl_xor(q1, 1); q2 += __shfl_xor(q2, 1); q3 += __shfl_xor(q3, 1);
    q0 += __shfl_xor(q0, 2); q1 += __shfl_xor(q1, 2); q2 += __shfl_xor(q2, 2); q3 += __shfl_xor(q3, 2);
    q0 += __shfl_xor(q0, 4); q1 += __shfl_xor(q1, 4); q2 += __shfl_xor(q2, 4); q3 += __shfl_xor(q3, 4);
    q0 += __shfl_xor(q0, 8); q1 += __shfl_xor(q1, 8); q2 += __shfl_xor(q2, 8); q3 += __shfl_xor(q3, 8);
    float a0 = q0 > 0.f ? q0 : NEG * q0;
    float a1 = q1 > 0.f ? q1 : NEG * q1;
    float a2 = q2 > 0.f ? q2 : NEG * q2;
    float a3 = q3 > 0.f ? q3 : NEG * q3;
    float nm = fmaxf(fmaxf(m, fmaxf(a0, a1)), fmaxf(a2, a3));
    float sc = __expf(m - nm);
    float w0 = __expf(a0 - nm), w1 = __expf(a1 - nm);
    float w2 = __expf(a2 - nm), w3 = __expf(a3 - nm);
    l = l * sc + w0 + w1 + w2 + w3;
    acc.x = acc.x * sc + w0 * xj0.x + w1 * xj1.x + w2 * xj2.x + w3 * xj3.x;
    acc.y = acc.y * sc + w0 * xj0.y + w1 * xj1.y + w2 * xj2.y + w3 * xj3.y;
    acc.z = acc.z * sc + w0 * xj0.z + w1 * xj1.z + w2 * xj2.z + w3 * xj3.z;
    acc.w = acc.w * sc + w0 * xj0.w + w1 * xj1.w + w2 * xj2.w + w3 * xj3.w;
    m = nm;
  }
  for (; e < e1; ++e) {
    int s = srt[e];
    float4 xj = make_float4(0.f, 0.f, 0.f, 0.f);
    if (act) xj = *(const float4*)&h[(size_t)s * 160 + head * OUTC + c4 * 4];
    float q = xi.x * xj.x + xi.y * xj.y + xi.z * xj.z + xi.w * xj.w;
    q += __shfl_xor(q, 1); q += __shfl_xor(q, 2); q += __shfl_xor(q, 4); q += __shfl_xor(q, 8);
    float al = q > 0.f ? q : NEG * q;
    float nm = fmaxf(m, al);
    float sc = __expf(m - nm), wt = __expf(al - nm);
    l = l * sc + wt;
    acc.x = acc.x * sc + wt * xj.x;
    acc.y = acc.y * sc + wt * xj.y;
    acc.z = acc.z * sc + wt * xj.z;
    acc.w = acc.w * sc + wt * xj.w;
    m = nm;
  }
  float inv = 1.f / (l + EPSV);
  if (act) {
    float4 res;
    res.x = acc.x * inv; res.y = acc.y * inv; res.z = acc.z * inv; res.w = acc.w * inv;
    *(float4*)&buf[wv][head * OUTC + c4 * 4] = res;
  }
  __syncthreads();
  const bool valid = lane < OUTC;
  float v = 0.f;
  if (valid)
    v = 0.25f * (buf[wv][lane] + buf[wv][OUTC + lane] + buf[wv][2 * OUTC + lane] +
                 buf[wv][3 * OUTC + lane]) + b2[lane];
  float t = valid ? v : -1e30f;
#pragma unroll
  for (int off = 32; off; off >>= 1) t = fmaxf(t, __shfl_xor(t, off));
  float ex = valid ? __expf(v - t) : 0.f;
  float s = ex;
#pragma unroll
  for (int off = 32; off; off >>= 1) s += __shfl_xor(s, off);
  float lse = t + __logf(s);
  if (valid) out[(size_t)node * OUTC + lane] = v - lse;
  if (blockIdx.x == 0 && threadIdx.x == 0) out[(size_t)Nn * OUTC] = 0.f;  // att_loss
}

extern "C" void kernel_launch(void* const* d_in, const int* in_sizes, int n_in,
                              void* d_out, int out_size, void* d_ws, size_t ws_size,
                              hipStream_t stream) {
  const float* x  = (const float*)d_in[0];
  const int*   ei = (const int*)d_in[1];
  const float* W1 = (const float*)d_in[2];
  const float* b1 = (const float*)d_in[3];
  const float* W2 = (const float*)d_in[4];
  const float* b2 = (const float*)d_in[5];
  float* out = (float*)d_out;

  const int Nn = in_sizes[0] / 512;  // 50000
  const int E  = in_sizes[1] / 2;    // 400000
  const int* esrc = ei;
  const int* edst = ei + E;
  const int NB = (Nn + 1023) / 1024;

  // workspace layout
  char* ws = (char*)d_ws;
  const size_t szH = (size_t)Nn * 256 * sizeof(float);  // 51.2 MB
  float* h1 = (float*)(ws);           // GEMM1 out [N,256] f32; reused as h2 [N,160] f32
  size_t off = szH;
  unsigned short* g1h = (unsigned short*)(ws + off); off += (size_t)Nn * 256 * 2;  // 25.6MB
  unsigned short* g1l = (unsigned short*)(ws + off); off += (size_t)Nn * 256 * 2;
  int* rp = (int*)(ws + off);   off += ((size_t)(Nn + 1) * 4 + 15) & ~(size_t)15;
  int* cnt = (int*)(ws + off);  off += ((size_t)Nn * 4 + 15) & ~(size_t)15;
  int* srt = (int*)(ws + off);  off += ((size_t)E * 4 + 15) & ~(size_t)15;
  int* bsum = (int*)(ws + off); off += 1024;
  unsigned short* Wh1 = (unsigned short*)(ws + off); off += (size_t)256 * 512 * 2;
  unsigned short* Wl1 = (unsigned short*)(ws + off); off += (size_t)256 * 512 * 2;
  unsigned short* Wh2 = (unsigned short*)(ws + off); off += (size_t)256 * 256 * 2;
  unsigned short* Wl2 = (unsigned short*)(ws + off); off += (size_t)256 * 256 * 2;
  float* h2 = h1;

  // CSR by destination (scanC zeroes cnt for scatter's cursor -- one less memset)
  hipMemsetAsync(cnt, 0, (size_t)Nn * sizeof(int), stream);
  hist_k<<<(E + 255) / 256, 256, 0, stream>>>(edst, cnt, E);
  scanA_k<<<NB, 1024, 0, stream>>>(cnt, rp, bsum, Nn);
  scanC_k<<<(Nn + 255) / 256, 256, 0, stream>>>(rp, bsum, cnt, Nn, NB);
  scatter_k<<<(E + 255) / 256, 256, 0, stream>>>(esrc, edst, rp, cnt, srt, E);

  // weight pre-split (merged)
  convW_k<<<768, 256, 0, stream>>>(W1, Wh1, Wl1, W2, Wh2, Wl2);

  // layer 1: A = x fp32 (read-time split), B = Wh1/Wl1
  gemm_dma<true, false>
      <<<dim3(2, (Nn + 127) / 128), 256, 0, stream>>>(x, nullptr, Wh1, Wl1, h1, Nn, 512);
  agg1_k<<<(Nn + 3) / 4, 256, 0, stream>>>(h1, rp, srt, b1, g1h, g1l, Nn);

  // layer 2: A = g1 pre-split bf16, compact [N,160] output
  gemm_dma<false, true>
      <<<dim3(2, (Nn + 127) / 128), 256, 0, stream>>>(g1h, g1l, Wh2, Wl2, h2, Nn, 256);
  agg2_k<<<(Nn + 3) / 4, 256, 0, stream>>>(h2, rp, srt, b2, out, Nn);
}

// Round 7
// 365.250 us; speedup vs baseline: 1.5943x; 1.0698x over previous
//
#include <hip/hip_runtime.h>
#include <hip/hip_fp16.h>
#include <cstddef>
#include <cstdint>

#define HEADS 4
#define OUTC  40
#define NEG   0.2f
#define EPSV  1e-16f

typedef __bf16 bf16x8 __attribute__((ext_vector_type(8)));
typedef float  floatx4 __attribute__((ext_vector_type(4)));

__device__ __forceinline__ void split_bf16(float a, unsigned& hi, unsigned& lo) {
  unsigned u = __float_as_uint(a);
  hi = u >> 16;                                   // RTZ high bf16
  float hf = __uint_as_float(u & 0xFFFF0000u);
  lo = __float_as_uint(a - hf) >> 16;             // RTZ residual bf16
}

// load 4 consecutive fp16 as one dwordx2 and widen to float4
__device__ __forceinline__ float4 ld_h4(const __half* p) {
  uint2 u = *(const uint2*)p;
  __half2 h0 = *(__half2*)&u.x, h1 = *(__half2*)&u.y;
  float2 f0 = __half22float2(h0), f1 = __half22float2(h1);
  return make_float4(f0.x, f0.y, f1.x, f1.y);
}

// async global->LDS DMA, 16B per lane. lds ptr must be wave-uniform base;
// HW writes lane i at base + i*16 (m97/m104).
__device__ __forceinline__ void dma16(const void* g, void* l) {
  __builtin_amdgcn_global_load_lds(
      (const __attribute__((address_space(1))) unsigned int*)g,
      (__attribute__((address_space(3))) unsigned int*)l, 16, 0, 0);
}

// ---------------- CSR build ----------------
__global__ void hist_k(const int* __restrict__ dst, int* __restrict__ cnt, int E) {
  int e = blockIdx.x * blockDim.x + threadIdx.x;
  if (e < E) atomicAdd(&cnt[dst[e]], 1);
}

__global__ __launch_bounds__(1024) void scanA_k(const int* __restrict__ cnt,
                                                int* __restrict__ rp,
                                                int* __restrict__ bsum, int n) {
  __shared__ int sh[1024];
  int i = blockIdx.x * 1024 + threadIdx.x;
  int v = (i < n) ? cnt[i] : 0;
  sh[threadIdx.x] = v;
  __syncthreads();
  for (int d = 1; d < 1024; d <<= 1) {
    int t = (threadIdx.x >= d) ? sh[threadIdx.x - d] : 0;
    __syncthreads();
    sh[threadIdx.x] += t;
    __syncthreads();
  }
  if (i < n) rp[i] = sh[threadIdx.x] - v;  // block-local exclusive
  if (threadIdx.x == 1023) bsum[blockIdx.x] = sh[1023];
}

// adds bsum prefix to rp; rp[n] = total. Also zeroes cnt (scatter cursor).
__global__ void scanC_k(int* __restrict__ rp, const int* __restrict__ bsum,
                        int* __restrict__ cnt, int n, int nb) {
  int i = blockIdx.x * blockDim.x + threadIdx.x;
  if (i < n) {
    int b = i >> 10;
    int off = 0;
    for (int j = 0; j < b; ++j) off += bsum[j];  // <=48 iters, L2-cached
    rp[i] += off;
    cnt[i] = 0;
  }
  if (i == 0) {
    int tot = 0;
    for (int j = 0; j < nb; ++j) tot += bsum[j];
    rp[n] = tot;
  }
}

__global__ void scatter_k(const int* __restrict__ src, const int* __restrict__ dst,
                          const int* __restrict__ rp, int* __restrict__ cur,
                          int* __restrict__ out, int E) {
  int e = blockIdx.x * blockDim.x + threadIdx.x;
  if (e < E) {
    int d = dst[e];
    int p = rp[d] + atomicAdd(&cur[d], 1);
    out[p] = src[e];
  }
}

// ---------------- weight pre-split (merged W1+W2): fp32 -> [n][K] bf16 hi/lo ----------
__global__ void convW_k(const float* __restrict__ W1, unsigned short* __restrict__ Wh1,
                        unsigned short* __restrict__ Wl1,
                        const float* __restrict__ W2, unsigned short* __restrict__ Wh2,
                        unsigned short* __restrict__ Wl2) {
  int id = blockIdx.x * 256 + threadIdx.x;
  if (id < 256 * 512) {  // W1 [512,256] -> [256][512]
    int n = id >> 9, k = id & 511;
    unsigned h, l;
    split_bf16(W1[k * 256 + n], h, l);
    Wh1[id] = (unsigned short)h;
    Wl1[id] = (unsigned short)l;
  } else {               // W2 [256,160] -> padded [256][256]
    int id2 = id - 256 * 512;
    int n = id2 >> 8, k = id2 & 255;
    int hh = n >> 6, c = n & 63;
    float a = (c < OUTC) ? W2[k * 160 + hh * OUTC + c] : 0.f;
    unsigned h, l;
    split_bf16(a, h, l);
    Wh2[id2] = (unsigned short)h;
    Wl2[id2] = (unsigned short)l;
  }
}

// ---------------- DMA GEMM: C[M,256] = A[M,K] @ B[K,256], fp16 output ----------
// K-loop = R14 (best measured GEMM variant; residency-insensitive 77-80us).
// R15: epilogue emits fp16 (halves C-write AND halves the downstream agg
// gather traffic -- h1/h2 are consumed only by the agg kernels).
//   A:    single buffer @0 (16KB), lgkm+barrier overwrite protocol
//   B-hi: double buffer @16384 + (k&1)*8192 ; B-lo: single buffer @32768
// Per-iter: DMA_Bhi(k+1) -> vmcnt(2) -> barrier1 -> ds_read tile k
//   -> lgkmcnt(0) -> barrier2 -> DMA_A(k+1)+DMA_Blo(k+1) -> 48 MFMA
// vmcnt audit (in-order, m135): at the wait, queue = [Bhi(k)2, A(k)4,
// Blo(k)2, Bhi(k+1)2] -> vmcnt(2) drains exactly tile k. Last iter vmcnt(0).
// Swizzle: write-side source permute + read-side XOR (R11).
template <bool A_FP32, bool COMPACT>
__global__ __launch_bounds__(256, 3) void gemm_dma(const void* Aptr_h, const void* Aptr_l,
                                                   const unsigned short* __restrict__ Bh,
                                                   const unsigned short* __restrict__ Bl,
                                                   __half* __restrict__ C, int M, int K) {
  __shared__ __align__(16) unsigned char lds[40960];
  const int tid = threadIdx.x;
  const int lane = tid & 63;
  const int w = tid >> 6;
  const int wr = w >> 1, wc = w & 1;
  const int row0 = blockIdx.y * 128;
  const int col0 = blockIdx.x * 128;
  const int fr = lane & 15, fq = lane >> 4;
  const int swz8 = fr & 7;
  const int swz4 = (fr & 3) ^ ((fr >> 2) & 1);
  const int srcA8 = (lane & 7) ^ (lane >> 3);
  const int srcB4 = (lane & 3) ^ ((lane >> 2) & 3) ^ ((lane >> 4) & 1);

  floatx4 acc[4][4];
#pragma unroll
  for (int i = 0; i < 4; ++i)
#pragma unroll
    for (int j = 0; j < 4; ++j) acc[i][j] = (floatx4){0.f, 0.f, 0.f, 0.f};

  const float* Af32 = (const float*)Aptr_h;
  const unsigned short* Agh = (const unsigned short*)Aptr_h;
  const unsigned short* Agl = (const unsigned short*)Aptr_l;

#define DMA_A(K0)                                                                   \
  do {                                                                              \
    if (A_FP32) {                                                                   \
      _Pragma("unroll") for (int t = 0; t < 4; ++t) {                               \
        int arow = w * 32 + t * 8 + (lane >> 3);                                    \
        int gr = row0 + arow; gr = gr < M ? gr : M - 1;                             \
        dma16(&Af32[(size_t)gr * K + (K0) + srcA8 * 4],                             \
              lds + (size_t)(w * 32 + t * 8) * 128);                                \
      }                                                                             \
    } else {                                                                        \
      _Pragma("unroll") for (int t = 0; t < 2; ++t) {                               \
        int arow = w * 32 + t * 16 + (lane >> 2);                                   \
        int gr = row0 + arow; gr = gr < M ? gr : M - 1;                             \
        size_t go = (size_t)gr * K + (K0) + srcB4 * 8;                              \
        dma16(&Agh[go], lds + (size_t)(w * 32 + t * 16) * 64);                      \
        dma16(&Agl[go], lds + 8192 + (size_t)(w * 32 + t * 16) * 64);               \
      }                                                                             \
    }                                                                               \
  } while (0)

#define DMA_BHI(K0, BASE)                                                           \
  do {                                                                              \
    _Pragma("unroll") for (int t = 0; t < 2; ++t) {                                 \
      int nrow = w * 32 + t * 16 + (lane >> 2);                                     \
      size_t go = (size_t)(col0 + nrow) * K + (K0) + srcB4 * 8;                     \
      dma16(&Bh[go], lds + (BASE) + (size_t)(w * 32 + t * 16) * 64);                \
    }                                                                               \
  } while (0)

#define DMA_BLO(K0)                                                                 \
  do {                                                                              \
    _Pragma("unroll") for (int t = 0; t < 2; ++t) {                                 \
      int nrow = w * 32 + t * 16 + (lane >> 2);                                     \
      size_t go = (size_t)(col0 + nrow) * K + (K0) + srcB4 * 8;                     \
      dma16(&Bl[go], lds + 32768 + (size_t)(w * 32 + t * 16) * 64);                 \
    }                                                                               \
  } while (0)

  const int nk = K >> 5;
  DMA_BHI(0, 16384);
  DMA_A(0);
  DMA_BLO(0);
  asm volatile("" ::: "memory");
  for (int k = 0; k < nk; ++k) {
    const int bbase = 16384 + ((k & 1) << 13);
    if (k + 1 < nk) {
      DMA_BHI((k + 1) << 5, 16384 + (((k + 1) & 1) << 13));
      asm volatile("s_waitcnt vmcnt(2)" ::: "memory");  // tile k done; Bhi(k+1) in flight
    } else {
      asm volatile("s_waitcnt vmcnt(0)" ::: "memory");
    }
    asm volatile("s_barrier" ::: "memory");  // tile k visible to all waves

    bf16x8 ah[4], al[4], bh[4], bl[4];
#pragma unroll
    for (int i = 0; i < 4; ++i) {
      int arow = wr * 64 + i * 16 + fr;
      if (A_FP32) {
        const unsigned char* pa = lds + (size_t)arow * 128;
        float4 v0 = *(const float4*)(pa + (((fq * 2) ^ swz8) * 16));
        float4 v1 = *(const float4*)(pa + (((fq * 2 + 1) ^ swz8) * 16));
        unsigned u0 = __float_as_uint(v0.x), u1 = __float_as_uint(v0.y);
        unsigned u2 = __float_as_uint(v0.z), u3 = __float_as_uint(v0.w);
        unsigned u4 = __float_as_uint(v1.x), u5 = __float_as_uint(v1.y);
        unsigned u6 = __float_as_uint(v1.z), u7 = __float_as_uint(v1.w);
        uint4 H;
        H.x = (u0 >> 16) | (u1 & 0xFFFF0000u);
        H.y = (u2 >> 16) | (u3 & 0xFFFF0000u);
        H.z = (u4 >> 16) | (u5 & 0xFFFF0000u);
        H.w = (u6 >> 16) | (u7 & 0xFFFF0000u);
        uint4 L;
        L.x = (__float_as_uint(v0.x - __uint_as_float(u0 & 0xFFFF0000u)) >> 16) |
              (__float_as_uint(v0.y - __uint_as_float(u1 & 0xFFFF0000u)) & 0xFFFF0000u);
        L.y = (__float_as_uint(v0.z - __uint_as_float(u2 & 0xFFFF0000u)) >> 16) |
              (__float_as_uint(v0.w - __uint_as_float(u3 & 0xFFFF0000u)) & 0xFFFF0000u);
        L.z = (__float_as_uint(v1.x - __uint_as_float(u4 & 0xFFFF0000u)) >> 16) |
              (__float_as_uint(v1.y - __uint_as_float(u5 & 0xFFFF0000u)) & 0xFFFF0000u);
        L.w = (__float_as_uint(v1.z - __uint_as_float(u6 & 0xFFFF0000u)) >> 16) |
              (__float_as_uint(v1.w - __uint_as_float(u7 & 0xFFFF0000u)) & 0xFFFF0000u);
        ah[i] = *(bf16x8*)&H;
        al[i] = *(bf16x8*)&L;
      } else {
        ah[i] = *(bf16x8*)(lds + (size_t)arow * 64 + ((fq ^ swz4) * 16));
        al[i] = *(bf16x8*)(lds + 8192 + (size_t)arow * 64 + ((fq ^ swz4) * 16));
      }
      int brow = wc * 64 + i * 16 + fr;
      bh[i] = *(bf16x8*)(lds + bbase + (size_t)brow * 64 + ((fq ^ swz4) * 16));
      bl[i] = *(bf16x8*)(lds + 32768 + (size_t)brow * 64 + ((fq ^ swz4) * 16));
    }
    asm volatile("s_waitcnt lgkmcnt(0)" ::: "memory");  // my reads retired
    asm volatile("s_barrier" ::: "memory");             // all reads retired -> A/Blo free
    if (k + 1 < nk) {                                   // overwrite for k+1
      DMA_A((k + 1) << 5);
      DMA_BLO((k + 1) << 5);
    }

#pragma unroll
    for (int i = 0; i < 4; ++i)
#pragma unroll
      for (int j = 0; j < 4; ++j) {
        acc[i][j] = __builtin_amdgcn_mfma_f32_16x16x32_bf16(ah[i], bh[j], acc[i][j], 0, 0, 0);
        acc[i][j] = __builtin_amdgcn_mfma_f32_16x16x32_bf16(ah[i], bl[j], acc[i][j], 0, 0, 0);
        acc[i][j] = __builtin_amdgcn_mfma_f32_16x16x32_bf16(al[i], bh[j], acc[i][j], 0, 0, 0);
      }
  }
#undef DMA_A
#undef DMA_BHI
#undef DMA_BLO

  // epilogue: C/D layout col=lane&15, row=(lane>>4)*4+r [m89]; fp16 output
#pragma unroll
  for (int i = 0; i < 4; ++i) {
    int grow_base = row0 + wr * 64 + i * 16 + fq * 4;
#pragma unroll
    for (int r = 0; r < 4; ++r) {
      int grow = grow_base + r;
      if (grow < M) {
        if (COMPACT) {
          int head = blockIdx.x * 2 + wc;
#pragma unroll
          for (int j = 0; j < 4; ++j) {
            int cc = j * 16 + fr;
            if (cc < OUTC)
              C[(size_t)grow * 160 + head * OUTC + cc] = __float2half_rn(acc[i][j][r]);
          }
        } else {
#pragma unroll
          for (int j = 0; j < 4; ++j)
            C[(size_t)grow * 256 + col0 + wc * 64 + j * 16 + fr] =
                __float2half_rn(acc[i][j][r]);
        }
      }
    }
  }
}

// ---------------- layer-1 agg: wave per node; fp16 gathers; bf16 hi/lo output ----
// R15: h1 is fp16 -> per-edge gather is 512B/row (was 1KB fp32). Aggregation
// stays fp32. Edge loop unrolled x4 (R12).
__global__ __launch_bounds__(256) void agg1_k(const __half* __restrict__ h,
                                              const int* __restrict__ rp,
                                              const int* __restrict__ srt,
                                              const float* __restrict__ b1,
                                              unsigned short* __restrict__ outh,
                                              unsigned short* __restrict__ outl, int Nn) {
  int wv = threadIdx.x >> 6, lane = threadIdx.x & 63;
  int node = blockIdx.x * 4 + wv;
  if (node >= Nn) node = Nn - 1;
  const float4 xi = ld_h4(&h[(size_t)node * 256 + lane * 4]);
  float p = xi.x * xi.x + xi.y * xi.y + xi.z * xi.z + xi.w * xi.w;
  p += __shfl_xor(p, 1); p += __shfl_xor(p, 2); p += __shfl_xor(p, 4); p += __shfl_xor(p, 8);
  float a = p > 0.f ? p : NEG * p;      // self-loop logit
  float m = a, l = 1.f;
  float4 acc = xi;
  const int e0 = rp[node], e1 = rp[node + 1];
  int e = e0;
  for (; e + 4 <= e1; e += 4) {
    int s0 = srt[e], s1 = srt[e + 1], s2 = srt[e + 2], s3 = srt[e + 3];
    const float4 xj0 = ld_h4(&h[(size_t)s0 * 256 + lane * 4]);
    const float4 xj1 = ld_h4(&h[(size_t)s1 * 256 + lane * 4]);
    const float4 xj2 = ld_h4(&h[(size_t)s2 * 256 + lane * 4]);
    const float4 xj3 = ld_h4(&h[(size_t)s3 * 256 + lane * 4]);
    float q0 = xi.x * xj0.x + xi.y * xj0.y + xi.z * xj0.z + xi.w * xj0.w;
    float q1 = xi.x * xj1.x + xi.y * xj1.y + xi.z * xj1.z + xi.w * xj1.w;
    float q2 = xi.x * xj2.x + xi.y * xj2.y + xi.z * xj2.z + xi.w * xj2.w;
    float q3 = xi.x * xj3.x + xi.y * xj3.y + xi.z * xj3.z + xi.w * xj3.w;
    q0 += __shfl_xor(q0, 1); q1 += __shfl_xor(q1, 1); q2 += __shfl_xor(q2, 1); q3 += __shfl_xor(q3, 1);
    q0 += __shfl_xor(q0, 2); q1 += __shfl_xor(q1, 2); q2 += __shfl_xor(q2, 2); q3 += __shfl_xor(q3, 2);
    q0 += __shfl_xor(q0, 4); q1 += __shfl_xor(q1, 4); q2 += __shfl_xor(q2, 4); q3 += __shfl_xor(q3, 4);
    q0 += __shfl_xor(q0, 8); q1 += __shfl_xor(q1, 8); q2 += __shfl_xor(q2, 8); q3 += __shfl_xor(q3, 8);
    float a0 = q0 > 0.f ? q0 : NEG * q0;
    float a1 = q1 > 0.f ? q1 : NEG * q1;
    float a2 = q2 > 0.f ? q2 : NEG * q2;
    float a3 = q3 > 0.f ? q3 : NEG * q3;
    float nm = fmaxf(fmaxf(m, fmaxf(a0, a1)), fmaxf(a2, a3));
    float sc = __expf(m - nm);
    float w0 = __expf(a0 - nm), w1 = __expf(a1 - nm);
    float w2 = __expf(a2 - nm), w3 = __expf(a3 - nm);
    l = l * sc + w0 + w1 + w2 + w3;
    acc.x = acc.x * sc + w0 * xj0.x + w1 * xj1.x + w2 * xj2.x + w3 * xj3.x;
    acc.y = acc.y * sc + w0 * xj0.y + w1 * xj1.y + w2 * xj2.y + w3 * xj3.y;
    acc.z = acc.z * sc + w0 * xj0.z + w1 * xj1.z + w2 * xj2.z + w3 * xj3.z;
    acc.w = acc.w * sc + w0 * xj0.w + w1 * xj1.w + w2 * xj2.w + w3 * xj3.w;
    m = nm;
  }
  for (; e < e1; ++e) {
    int s = srt[e];
    const float4 xj = ld_h4(&h[(size_t)s * 256 + lane * 4]);
    float q = xi.x * xj.x + xi.y * xj.y + xi.z * xj.z + xi.w * xj.w;
    q += __shfl_xor(q, 1); q += __shfl_xor(q, 2); q += __shfl_xor(q, 4); q += __shfl_xor(q, 8);
    float al = q > 0.f ? q : NEG * q;
    float nm = fmaxf(m, al);
    float sc = __expf(m - nm), wt = __expf(al - nm);
    l = l * sc + wt;
    acc.x = acc.x * sc + wt * xj.x;
    acc.y = acc.y * sc + wt * xj.y;
    acc.z = acc.z * sc + wt * xj.z;
    acc.w = acc.w * sc + wt * xj.w;
    m = nm;
  }
  float inv = 1.f / (l + EPSV);
  const float4 bb = *(const float4*)&b1[lane * 4];
  float4 o;
  o.x = acc.x * inv + bb.x;
  o.y = acc.y * inv + bb.y;
  o.z = acc.z * inv + bb.z;
  o.w = acc.w * inv + bb.w;
  o.x = o.x > 0.f ? o.x : __expf(o.x) - 1.f;
  o.y = o.y > 0.f ? o.y : __expf(o.y) - 1.f;
  o.z = o.z > 0.f ? o.z : __expf(o.z) - 1.f;
  o.w = o.w > 0.f ? o.w : __expf(o.w) - 1.f;
  unsigned h0, l0, h1, l1, h2, l2, h3, l3;
  split_bf16(o.x, h0, l0);
  split_bf16(o.y, h1, l1);
  split_bf16(o.z, h2, l2);
  split_bf16(o.w, h3, l3);
  size_t base = (size_t)node * 256 + lane * 4;
  *(uint2*)&outh[base] = make_uint2(h0 | (h1 << 16), h2 | (h3 << 16));
  *(uint2*)&outl[base] = make_uint2(l0 | (l1 << 16), l2 | (l3 << 16));
}

// ---------------- layer-2 agg (compact [N,160] fp16 input) + head-mean + log_softmax ----
__global__ __launch_bounds__(256) void agg2_k(const __half* __restrict__ h,
                                              const int* __restrict__ rp,
                                              const int* __restrict__ srt,
                                              const float* __restrict__ b2,
                                              float* __restrict__ out, int Nn) {
  __shared__ float buf[4][160];
  int wv = threadIdx.x >> 6, lane = threadIdx.x & 63;
  int node = blockIdx.x * 4 + wv;
  if (node >= Nn) node = Nn - 1;
  const int head = lane >> 4, c4 = lane & 15;
  const bool act = c4 < 10;  // 10 lanes x 4 fp16 = 40 channels per head
  float4 xi = make_float4(0.f, 0.f, 0.f, 0.f);
  if (act) xi = ld_h4(&h[(size_t)node * 160 + head * OUTC + c4 * 4]);
  float p = xi.x * xi.x + xi.y * xi.y + xi.z * xi.z + xi.w * xi.w;
  p += __shfl_xor(p, 1); p += __shfl_xor(p, 2); p += __shfl_xor(p, 4); p += __shfl_xor(p, 8);
  float a = p > 0.f ? p : NEG * p;
  float m = a, l = 1.f;
  float4 acc = xi;
  const int e0 = rp[node], e1 = rp[node + 1];
  int e = e0;
  for (; e + 4 <= e1; e += 4) {
    int s0 = srt[e], s1 = srt[e + 1], s2 = srt[e + 2], s3 = srt[e + 3];
    float4 xj0 = make_float4(0.f, 0.f, 0.f, 0.f);
    float4 xj1 = make_float4(0.f, 0.f, 0.f, 0.f);
    float4 xj2 = make_float4(0.f, 0.f, 0.f, 0.f);
    float4 xj3 = make_float4(0.f, 0.f, 0.f, 0.f);
    if (act) {
      xj0 = ld_h4(&h[(size_t)s0 * 160 + head * OUTC + c4 * 4]);
      xj1 = ld_h4(&h[(size_t)s1 * 160 + head * OUTC + c4 * 4]);
      xj2 = ld_h4(&h[(size_t)s2 * 160 + head * OUTC + c4 * 4]);
      xj3 = ld_h4(&h[(size_t)s3 * 160 + head * OUTC + c4 * 4]);
    }
    float q0 = xi.x * xj0.x + xi.y * xj0.y + xi.z * xj0.z + xi.w * xj0.w;
    float q1 = xi.x * xj1.x + xi.y * xj1.y + xi.z * xj1.z + xi.w * xj1.w;
    float q2 = xi.x * xj2.x + xi.y * xj2.y + xi.z * xj2.z + xi.w * xj2.w;
    float q3 = xi.x * xj3.x + xi.y * xj3.y + xi.z * xj3.z + xi.w * xj3.w;
    q0 += __shfl_xor(q0, 1); q1 += __shfl_xor(q1, 1); q2 += __shfl_xor(q2, 1); q3 += __shfl_xor(q3, 1);
    q0 += __shfl_xor(q0, 2); q1 += __shfl_xor(q1, 2); q2 += __shfl_xor(q2, 2); q3 += __shfl_xor(q3, 2);
    q0 += __shfl_xor(q0, 4); q1 += __shfl_xor(q1, 4); q2 += __shfl_xor(q2, 4); q3 += __shfl_xor(q3, 4);
    q0 += __shfl_xor(q0, 8); q1 += __shfl_xor(q1, 8); q2 += __shfl_xor(q2, 8); q3 += __shfl_xor(q3, 8);
    float a0 = q0 > 0.f ? q0 : NEG * q0;
    float a1 = q1 > 0.f ? q1 : NEG * q1;
    float a2 = q2 > 0.f ? q2 : NEG * q2;
    float a3 = q3 > 0.f ? q3 : NEG * q3;
    float nm = fmaxf(fmaxf(m, fmaxf(a0, a1)), fmaxf(a2, a3));
    float sc = __expf(m - nm);
    float w0 = __expf(a0 - nm), w1 = __expf(a1 - nm);
    float w2 = __expf(a2 - nm), w3 = __expf(a3 - nm);
    l = l * sc + w0 + w1 + w2 + w3;
    acc.x = acc.x * sc + w0 * xj0.x + w1 * xj1.x + w2 * xj2.x + w3 * xj3.x;
    acc.y = acc.y * sc + w0 * xj0.y + w1 * xj1.y + w2 * xj2.y + w3 * xj3.y;
    acc.z = acc.z * sc + w0 * xj0.z + w1 * xj1.z + w2 * xj2.z + w3 * xj3.z;
    acc.w = acc.w * sc + w0 * xj0.w + w1 * xj1.w + w2 * xj2.w + w3 * xj3.w;
    m = nm;
  }
  for (; e < e1; ++e) {
    int s = srt[e];
    float4 xj = make_float4(0.f, 0.f, 0.f, 0.f);
    if (act) xj = ld_h4(&h[(size_t)s * 160 + head * OUTC + c4 * 4]);
    float q = xi.x * xj.x + xi.y * xj.y + xi.z * xj.z + xi.w * xj.w;
    q += __shfl_xor(q, 1); q += __shfl_xor(q, 2); q += __shfl_xor(q, 4); q += __shfl_xor(q, 8);
    float al = q > 0.f ? q : NEG * q;
    float nm = fmaxf(m, al);
    float sc = __expf(m - nm), wt = __expf(al - nm);
    l = l * sc + wt;
    acc.x = acc.x * sc + wt * xj.x;
    acc.y = acc.y * sc + wt * xj.y;
    acc.z = acc.z * sc + wt * xj.z;
    acc.w = acc.w * sc + wt * xj.w;
    m = nm;
  }
  float inv = 1.f / (l + EPSV);
  if (act) {
    float4 res;
    res.x = acc.x * inv; res.y = acc.y * inv; res.z = acc.z * inv; res.w = acc.w * inv;
    *(float4*)&buf[wv][head * OUTC + c4 * 4] = res;
  }
  __syncthreads();
  const bool valid = lane < OUTC;
  float v = 0.f;
  if (valid)
    v = 0.25f * (buf[wv][lane] + buf[wv][OUTC + lane] + buf[wv][2 * OUTC + lane] +
                 buf[wv][3 * OUTC + lane]) + b2[lane];
  float t = valid ? v : -1e30f;
#pragma unroll
  for (int off = 32; off; off >>= 1) t = fmaxf(t, __shfl_xor(t, off));
  float ex = valid ? __expf(v - t) : 0.f;
  float s = ex;
#pragma unroll
  for (int off = 32; off; off >>= 1) s += __shfl_xor(s, off);
  float lse = t + __logf(s);
  if (valid) out[(size_t)node * OUTC + lane] = v - lse;
  if (blockIdx.x == 0 && threadIdx.x == 0) out[(size_t)Nn * OUTC] = 0.f;  // att_loss
}

extern "C" void kernel_launch(void* const* d_in, const int* in_sizes, int n_in,
                              void* d_out, int out_size, void* d_ws, size_t ws_size,
                              hipStream_t stream) {
  const float* x  = (const float*)d_in[0];
  const int*   ei = (const int*)d_in[1];
  const float* W1 = (const float*)d_in[2];
  const float* b1 = (const float*)d_in[3];
  const float* W2 = (const float*)d_in[4];
  const float* b2 = (const float*)d_in[5];
  float* out = (float*)d_out;

  const int Nn = in_sizes[0] / 512;  // 50000
  const int E  = in_sizes[1] / 2;    // 400000
  const int* esrc = ei;
  const int* edst = ei + E;
  const int NB = (Nn + 1023) / 1024;

  // workspace layout (h region now holds fp16; same reservation as before)
  char* ws = (char*)d_ws;
  const size_t szH = (size_t)Nn * 256 * sizeof(float);  // 51.2 MB reservation
  __half* h1 = (__half*)(ws);         // GEMM1 out [N,256] fp16; reused as h2 [N,160] fp16
  size_t off = szH;
  unsigned short* g1h = (unsigned short*)(ws + off); off += (size_t)Nn * 256 * 2;  // 25.6MB
  unsigned short* g1l = (unsigned short*)(ws + off); off += (size_t)Nn * 256 * 2;
  int* rp = (int*)(ws + off);   off += ((size_t)(Nn + 1) * 4 + 15) & ~(size_t)15;
  int* cnt = (int*)(ws + off);  off += ((size_t)Nn * 4 + 15) & ~(size_t)15;
  int* srt = (int*)(ws + off);  off += ((size_t)E * 4 + 15) & ~(size_t)15;
  int* bsum = (int*)(ws + off); off += 1024;
  unsigned short* Wh1 = (unsigned short*)(ws + off); off += (size_t)256 * 512 * 2;
  unsigned short* Wl1 = (unsigned short*)(ws + off); off += (size_t)256 * 512 * 2;
  unsigned short* Wh2 = (unsigned short*)(ws + off); off += (size_t)256 * 256 * 2;
  unsigned short* Wl2 = (unsigned short*)(ws + off); off += (size_t)256 * 256 * 2;
  __half* h2 = h1;

  // CSR by destination (scanC zeroes cnt for scatter's cursor)
  hipMemsetAsync(cnt, 0, (size_t)Nn * sizeof(int), stream);
  hist_k<<<(E + 255) / 256, 256, 0, stream>>>(edst, cnt, E);
  scanA_k<<<NB, 1024, 0, stream>>>(cnt, rp, bsum, Nn);
  scanC_k<<<(Nn + 255) / 256, 256, 0, stream>>>(rp, bsum, cnt, Nn, NB);
  scatter_k<<<(E + 255) / 256, 256, 0, stream>>>(esrc, edst, rp, cnt, srt, E);

  // weight pre-split (merged)
  convW_k<<<768, 256, 0, stream>>>(W1, Wh1, Wl1, W2, Wh2, Wl2);

  // layer 1: A = x fp32 (read-time split), B = Wh1/Wl1; fp16 h1 out
  gemm_dma<true, false>
      <<<dim3(2, (Nn + 127) / 128), 256, 0, stream>>>(x, nullptr, Wh1, Wl1, h1, Nn, 512);
  agg1_k<<<(Nn + 3) / 4, 256, 0, stream>>>(h1, rp, srt, b1, g1h, g1l, Nn);

  // layer 2: A = g1 pre-split bf16, compact [N,160] fp16 out
  gemm_dma<false, true>
      <<<dim3(2, (Nn + 127) / 128), 256, 0, stream>>>(g1h, g1l, Wh2, Wl2, h2, Nn, 256);
  agg2_k<<<(Nn + 3) / 4, 256, 0, stream>>>(h2, rp, srt, b2, out, Nn);
}

// Round 9
// 355.255 us; speedup vs baseline: 1.6392x; 1.0281x over previous
//
#include <hip/hip_runtime.h>
#include <hip/hip_fp16.h>
#include <cstddef>
#include <cstdint>

#define HEADS 4
#define OUTC  40
#define NEG   0.2f
#define EPSV  1e-16f

typedef _Float16 f16x8 __attribute__((ext_vector_type(8)));
typedef __fp16   h16x2 __attribute__((ext_vector_type(2)));  // cvt_pkrtz return type
typedef float    floatx4 __attribute__((ext_vector_type(4)));

// fp16 hi/lo split (RN): hi = fp16(a), lo = fp16(a - hi). Combined ~22-bit mantissa.
__device__ __forceinline__ void split_f16(float a, unsigned short& hi, unsigned short& lo) {
  __half h = __float2half_rn(a);
  float r = a - __half2float(h);
  __half l = __float2half_rn(r);
  hi = __half_as_ushort(h);
  lo = __half_as_ushort(l);
}

// pack 8 fp32 -> 8 fp16 (RTZ, 4 instructions)
__device__ __forceinline__ f16x8 pack8(float4 v0, float4 v1) {
  h16x2 p0 = __builtin_amdgcn_cvt_pkrtz(v0.x, v0.y);
  h16x2 p1 = __builtin_amdgcn_cvt_pkrtz(v0.z, v0.w);
  h16x2 p2 = __builtin_amdgcn_cvt_pkrtz(v1.x, v1.y);
  h16x2 p3 = __builtin_amdgcn_cvt_pkrtz(v1.z, v1.w);
  uint4 u;
  u.x = *(unsigned*)&p0; u.y = *(unsigned*)&p1;
  u.z = *(unsigned*)&p2; u.w = *(unsigned*)&p3;
  return *(f16x8*)&u;
}

// load 4 consecutive fp16 as one dwordx2 and widen to float4
__device__ __forceinline__ float4 ld_h4(const __half* p) {
  uint2 u = *(const uint2*)p;
  __half2 h0 = *(__half2*)&u.x, h1 = *(__half2*)&u.y;
  float2 f0 = __half22float2(h0), f1 = __half22float2(h1);
  return make_float4(f0.x, f0.y, f1.x, f1.y);
}

// async global->LDS DMA, 16B per lane. lds ptr must be wave-uniform base;
// HW writes lane i at base + i*16 (m97/m104).
__device__ __forceinline__ void dma16(const void* g, void* l) {
  __builtin_amdgcn_global_load_lds(
      (const __attribute__((address_space(1))) unsigned int*)g,
      (__attribute__((address_space(3))) unsigned int*)l, 16, 0, 0);
}

// ---------------- CSR build ----------------
__global__ void hist_k(const int* __restrict__ dst, int* __restrict__ cnt, int E) {
  int e = blockIdx.x * blockDim.x + threadIdx.x;
  if (e < E) atomicAdd(&cnt[dst[e]], 1);
}

__global__ __launch_bounds__(1024) void scanA_k(const int* __restrict__ cnt,
                                                int* __restrict__ rp,
                                                int* __restrict__ bsum, int n) {
  __shared__ int sh[1024];
  int i = blockIdx.x * 1024 + threadIdx.x;
  int v = (i < n) ? cnt[i] : 0;
  sh[threadIdx.x] = v;
  __syncthreads();
  for (int d = 1; d < 1024; d <<= 1) {
    int t = (threadIdx.x >= d) ? sh[threadIdx.x - d] : 0;
    __syncthreads();
    sh[threadIdx.x] += t;
    __syncthreads();
  }
  if (i < n) rp[i] = sh[threadIdx.x] - v;  // block-local exclusive
  if (threadIdx.x == 1023) bsum[blockIdx.x] = sh[1023];
}

// adds bsum prefix to rp; rp[n] = total. Also zeroes cnt (scatter cursor).
__global__ void scanC_k(int* __restrict__ rp, const int* __restrict__ bsum,
                        int* __restrict__ cnt, int n, int nb) {
  int i = blockIdx.x * blockDim.x + threadIdx.x;
  if (i < n) {
    int b = i >> 10;
    int off = 0;
    for (int j = 0; j < b; ++j) off += bsum[j];  // <=48 iters, L2-cached
    rp[i] += off;
    cnt[i] = 0;
  }
  if (i == 0) {
    int tot = 0;
    for (int j = 0; j < nb; ++j) tot += bsum[j];
    rp[n] = tot;
  }
}

__global__ void scatter_k(const int* __restrict__ src, const int* __restrict__ dst,
                          const int* __restrict__ rp, int* __restrict__ cur,
                          int* __restrict__ out, int E) {
  int e = blockIdx.x * blockDim.x + threadIdx.x;
  if (e < E) {
    int d = dst[e];
    int p = rp[d] + atomicAdd(&cur[d], 1);
    out[p] = src[e];
  }
}

// ---------------- weight pre-split (merged W1+W2): fp32 -> [n][K] fp16 hi/lo ----------
// R16: fp16 hi/lo (was bf16). fp16 pair = 22-bit mantissa; |W| <= 0.16 >> fp16
// min-normal, residual representable. Enables 2-MFMA f16 path in the GEMMs.
__global__ void convW_k(const float* __restrict__ W1, unsigned short* __restrict__ Wh1,
                        unsigned short* __restrict__ Wl1,
                        const float* __restrict__ W2, unsigned short* __restrict__ Wh2,
                        unsigned short* __restrict__ Wl2) {
  int id = blockIdx.x * 256 + threadIdx.x;
  if (id < 256 * 512) {  // W1 [512,256] -> [256][512]
    int n = id >> 9, k = id & 511;
    unsigned short h, l;
    split_f16(W1[k * 256 + n], h, l);
    Wh1[id] = h;
    Wl1[id] = l;
  } else {               // W2 [256,160] -> padded [256][256]
    int id2 = id - 256 * 512;
    int n = id2 >> 8, k = id2 & 255;
    int hh = n >> 6, c = n & 63;
    float a = (c < OUTC) ? W2[k * 160 + hh * OUTC + c] : 0.f;
    unsigned short h, l;
    split_f16(a, h, l);
    Wh2[id2] = h;
    Wl2[id2] = l;
  }
}

// ---------------- DMA GEMM: C[M,256] = A[M,K] @ B[K,256], fp16 everywhere ----------
// R16: numeric format change inside the R14 K-loop (protocol untouched):
//   A: SINGLE precision-path -- fp16 (GEMM1: fp32 in LDS, cvt_pkrtz at read;
//      GEMM2: fp16 direct from agg1). Error <= 2^-10 rel -> ~5e-4 on h1,
//      ~5e-3 on final logits (audited vs 0.03125 absmax).
//   B: fp16 hi/lo split (22-bit effective) -> 2 MFMAs per fragment pair
//      (mfma_f32_16x16x32_f16), 32/iter vs 48, and A-repack is 4 cvt_pkrtz
//      vs ~24 bit-ops.
// LDS: A_FP32: A fp32 16KB @0, Bhi dbuf @16384+(k&1)*8192, Blo @32768 (40KB)
//      !A_FP32: A fp16  8KB @0, Bhi dbuf @8192+(k&1)*8192,  Blo @24576 (32KB)
// Per-iter: DMA_Bhi(k+1) -> vmcnt(2) -> barrier1 -> ds_read tile k
//   -> lgkmcnt(0) -> barrier2 -> DMA_A(k+1)+DMA_Blo(k+1) -> 32 MFMA
// vmcnt audit (in-order, m135): at the wait, queue = [Bhi(k)2, A(k)4|2,
// Blo(k)2, Bhi(k+1)2] -> vmcnt(2) drains exactly tile k. Last iter vmcnt(0).
// Swizzle: write-side source permute + read-side XOR (R11).
template <bool A_FP32, bool COMPACT>
__global__ __launch_bounds__(256, 3) void gemm_dma(const void* Aptr,
                                                   const unsigned short* __restrict__ Bh,
                                                   const unsigned short* __restrict__ Bl,
                                                   __half* __restrict__ C, int M, int K) {
  constexpr int BHI0 = A_FP32 ? 16384 : 8192;
  constexpr int BLO0 = BHI0 + 16384;
  __shared__ __align__(16) unsigned char lds[A_FP32 ? 40960 : 32768];
  const int tid = threadIdx.x;
  const int lane = tid & 63;
  const int w = tid >> 6;
  const int wr = w >> 1, wc = w & 1;
  const int row0 = blockIdx.y * 128;
  const int col0 = blockIdx.x * 128;
  const int fr = lane & 15, fq = lane >> 4;
  const int swz8 = fr & 7;
  const int swz4 = (fr & 3) ^ ((fr >> 2) & 1);
  const int srcA8 = (lane & 7) ^ (lane >> 3);
  const int srcB4 = (lane & 3) ^ ((lane >> 2) & 3) ^ ((lane >> 4) & 1);

  floatx4 acc[4][4];
#pragma unroll
  for (int i = 0; i < 4; ++i)
#pragma unroll
    for (int j = 0; j < 4; ++j) acc[i][j] = (floatx4){0.f, 0.f, 0.f, 0.f};

  const float* Af32 = (const float*)Aptr;
  const unsigned short* Ag16 = (const unsigned short*)Aptr;

  // A tile, single buffer @0: 4 DMA insts (fp32) or 2 (fp16)
#define DMA_A(K0)                                                                   \
  do {                                                                              \
    if (A_FP32) {                                                                   \
      _Pragma("unroll") for (int t = 0; t < 4; ++t) {                               \
        int arow = w * 32 + t * 8 + (lane >> 3);                                    \
        int gr = row0 + arow; gr = gr < M ? gr : M - 1;                             \
        dma16(&Af32[(size_t)gr * K + (K0) + srcA8 * 4],                             \
              lds + (size_t)(w * 32 + t * 8) * 128);                                \
      }                                                                             \
    } else {                                                                        \
      _Pragma("unroll") for (int t = 0; t < 2; ++t) {                               \
        int arow = w * 32 + t * 16 + (lane >> 2);                                   \
        int gr = row0 + arow; gr = gr < M ? gr : M - 1;                             \
        dma16(&Ag16[(size_t)gr * K + (K0) + srcB4 * 8],                             \
              lds + (size_t)(w * 32 + t * 16) * 64);                                \
      }                                                                             \
    }                                                                               \
  } while (0)

  // B-hi tile into dbuf at BASE: 2 DMA insts
#define DMA_BHI(K0, BASE)                                                           \
  do {                                                                              \
    _Pragma("unroll") for (int t = 0; t < 2; ++t) {                                 \
      int nrow = w * 32 + t * 16 + (lane >> 2);                                     \
      size_t go = (size_t)(col0 + nrow) * K + (K0) + srcB4 * 8;                     \
      dma16(&Bh[go], lds + (BASE) + (size_t)(w * 32 + t * 16) * 64);                \
    }                                                                               \
  } while (0)

  // B-lo tile, single buffer @BLO0: 2 DMA insts
#define DMA_BLO(K0)                                                                 \
  do {                                                                              \
    _Pragma("unroll") for (int t = 0; t < 2; ++t) {                                 \
      int nrow = w * 32 + t * 16 + (lane >> 2);                                     \
      size_t go = (size_t)(col0 + nrow) * K + (K0) + srcB4 * 8;                     \
      dma16(&Bl[go], lds + BLO0 + (size_t)(w * 32 + t * 16) * 64);                  \
    }                                                                               \
  } while (0)

  const int nk = K >> 5;
  DMA_BHI(0, BHI0);
  DMA_A(0);
  DMA_BLO(0);
  asm volatile("" ::: "memory");
  for (int k = 0; k < nk; ++k) {
    const int bbase = BHI0 + ((k & 1) << 13);
    if (k + 1 < nk) {
      DMA_BHI((k + 1) << 5, BHI0 + (((k + 1) & 1) << 13));
      asm volatile("s_waitcnt vmcnt(2)" ::: "memory");  // tile k done; Bhi(k+1) in flight
    } else {
      asm volatile("s_waitcnt vmcnt(0)" ::: "memory");
    }
    asm volatile("s_barrier" ::: "memory");  // tile k visible to all waves

    f16x8 a[4], bh[4], bl[4];
#pragma unroll
    for (int i = 0; i < 4; ++i) {
      int arow = wr * 64 + i * 16 + fr;
      if (A_FP32) {
        const unsigned char* pa = lds + (size_t)arow * 128;
        float4 v0 = *(const float4*)(pa + (((fq * 2) ^ swz8) * 16));
        float4 v1 = *(const float4*)(pa + (((fq * 2 + 1) ^ swz8) * 16));
        a[i] = pack8(v0, v1);
      } else {
        a[i] = *(f16x8*)(lds + (size_t)arow * 64 + ((fq ^ swz4) * 16));
      }
      int brow = wc * 64 + i * 16 + fr;
      bh[i] = *(f16x8*)(lds + bbase + (size_t)brow * 64 + ((fq ^ swz4) * 16));
      bl[i] = *(f16x8*)(lds + BLO0 + (size_t)brow * 64 + ((fq ^ swz4) * 16));
    }
    asm volatile("s_waitcnt lgkmcnt(0)" ::: "memory");  // my reads retired
    asm volatile("s_barrier" ::: "memory");             // all reads retired -> A/Blo free
    if (k + 1 < nk) {                                   // overwrite for k+1
      DMA_A((k + 1) << 5);
      DMA_BLO((k + 1) << 5);
    }

#pragma unroll
    for (int i = 0; i < 4; ++i)
#pragma unroll
      for (int j = 0; j < 4; ++j) {
        acc[i][j] = __builtin_amdgcn_mfma_f32_16x16x32_f16(a[i], bh[j], acc[i][j], 0, 0, 0);
        acc[i][j] = __builtin_amdgcn_mfma_f32_16x16x32_f16(a[i], bl[j], acc[i][j], 0, 0, 0);
      }
  }
#undef DMA_A
#undef DMA_BHI
#undef DMA_BLO

  // epilogue: C/D layout col=lane&15, row=(lane>>4)*4+r [m89]; fp16 output
#pragma unroll
  for (int i = 0; i < 4; ++i) {
    int grow_base = row0 + wr * 64 + i * 16 + fq * 4;
#pragma unroll
    for (int r = 0; r < 4; ++r) {
      int grow = grow_base + r;
      if (grow < M) {
        if (COMPACT) {
          int head = blockIdx.x * 2 + wc;
#pragma unroll
          for (int j = 0; j < 4; ++j) {
            int cc = j * 16 + fr;
            if (cc < OUTC)
              C[(size_t)grow * 160 + head * OUTC + cc] = __float2half_rn(acc[i][j][r]);
          }
        } else {
#pragma unroll
          for (int j = 0; j < 4; ++j)
            C[(size_t)grow * 256 + col0 + wc * 64 + j * 16 + fr] =
                __float2half_rn(acc[i][j][r]);
        }
      }
    }
  }
}

// ---------------- layer-1 agg: wave per node; fp16 gathers; single fp16 output ----
// R16: output is ONE fp16 array (was bf16 hi/lo x2): write 51->25.6MB, no
// split math. GEMM2 consumes it directly (fp16 A path).
__global__ __launch_bounds__(256) void agg1_k(const __half* __restrict__ h,
                                              const int* __restrict__ rp,
                                              const int* __restrict__ srt,
                                              const float* __restrict__ b1,
                                              __half* __restrict__ g1, int Nn) {
  int wv = threadIdx.x >> 6, lane = threadIdx.x & 63;
  int node = blockIdx.x * 4 + wv;
  if (node >= Nn) node = Nn - 1;
  const float4 xi = ld_h4(&h[(size_t)node * 256 + lane * 4]);
  float p = xi.x * xi.x + xi.y * xi.y + xi.z * xi.z + xi.w * xi.w;
  p += __shfl_xor(p, 1); p += __shfl_xor(p, 2); p += __shfl_xor(p, 4); p += __shfl_xor(p, 8);
  float a = p > 0.f ? p : NEG * p;      // self-loop logit
  float m = a, l = 1.f;
  float4 acc = xi;
  const int e0 = rp[node], e1 = rp[node + 1];
  int e = e0;
  for (; e + 4 <= e1; e += 4) {
    int s0 = srt[e], s1 = srt[e + 1], s2 = srt[e + 2], s3 = srt[e + 3];
    const float4 xj0 = ld_h4(&h[(size_t)s0 * 256 + lane * 4]);
    const float4 xj1 = ld_h4(&h[(size_t)s1 * 256 + lane * 4]);
    const float4 xj2 = ld_h4(&h[(size_t)s2 * 256 + lane * 4]);
    const float4 xj3 = ld_h4(&h[(size_t)s3 * 256 + lane * 4]);
    float q0 = xi.x * xj0.x + xi.y * xj0.y + xi.z * xj0.z + xi.w * xj0.w;
    float q1 = xi.x * xj1.x + xi.y * xj1.y + xi.z * xj1.z + xi.w * xj1.w;
    float q2 = xi.x * xj2.x + xi.y * xj2.y + xi.z * xj2.z + xi.w * xj2.w;
    float q3 = xi.x * xj3.x + xi.y * xj3.y + xi.z * xj3.z + xi.w * xj3.w;
    q0 += __shfl_xor(q0, 1); q1 += __shfl_xor(q1, 1); q2 += __shfl_xor(q2, 1); q3 += __shfl_xor(q3, 1);
    q0 += __shfl_xor(q0, 2); q1 += __shfl_xor(q1, 2); q2 += __shfl_xor(q2, 2); q3 += __shfl_xor(q3, 2);
    q0 += __shfl_xor(q0, 4); q1 += __shfl_xor(q1, 4); q2 += __shfl_xor(q2, 4); q3 += __shfl_xor(q3, 4);
    q0 += __shfl_xor(q0, 8); q1 += __shfl_xor(q1, 8); q2 += __shfl_xor(q2, 8); q3 += __shfl_xor(q3, 8);
    float a0 = q0 > 0.f ? q0 : NEG * q0;
    float a1 = q1 > 0.f ? q1 : NEG * q1;
    float a2 = q2 > 0.f ? q2 : NEG * q2;
    float a3 = q3 > 0.f ? q3 : NEG * q3;
    float nm = fmaxf(fmaxf(m, fmaxf(a0, a1)), fmaxf(a2, a3));
    float sc = __expf(m - nm);
    float w0 = __expf(a0 - nm), w1 = __expf(a1 - nm);
    float w2 = __expf(a2 - nm), w3 = __expf(a3 - nm);
    l = l * sc + w0 + w1 + w2 + w3;
    acc.x = acc.x * sc + w0 * xj0.x + w1 * xj1.x + w2 * xj2.x + w3 * xj3.x;
    acc.y = acc.y * sc + w0 * xj0.y + w1 * xj1.y + w2 * xj2.y + w3 * xj3.y;
    acc.z = acc.z * sc + w0 * xj0.z + w1 * xj1.z + w2 * xj2.z + w3 * xj3.z;
    acc.w = acc.w * sc + w0 * xj0.w + w1 * xj1.w + w2 * xj2.w + w3 * xj3.w;
    m = nm;
  }
  for (; e < e1; ++e) {
    int s = srt[e];
    const float4 xj = ld_h4(&h[(size_t)s * 256 + lane * 4]);
    float q = xi.x * xj.x + xi.y * xj.y + xi.z * xj.z + xi.w * xj.w;
    q += __shfl_xor(q, 1); q += __shfl_xor(q, 2); q += __shfl_xor(q, 4); q += __shfl_xor(q, 8);
    float al = q > 0.f ? q : NEG * q;
    float nm = fmaxf(m, al);
    float sc = __expf(m - nm), wt = __expf(al - nm);
    l = l * sc + wt;
    acc.x = acc.x * sc + wt * xj.x;
    acc.y = acc.y * sc + wt * xj.y;
    acc.z = acc.z * sc + wt * xj.z;
    acc.w = acc.w * sc + wt * xj.w;
    m = nm;
  }
  float inv = 1.f / (l + EPSV);
  const float4 bb = *(const float4*)&b1[lane * 4];
  float4 o;
  o.x = acc.x * inv + bb.x;
  o.y = acc.y * inv + bb.y;
  o.z = acc.z * inv + bb.z;
  o.w = acc.w * inv + bb.w;
  o.x = o.x > 0.f ? o.x : __expf(o.x) - 1.f;
  o.y = o.y > 0.f ? o.y : __expf(o.y) - 1.f;
  o.z = o.z > 0.f ? o.z : __expf(o.z) - 1.f;
  o.w = o.w > 0.f ? o.w : __expf(o.w) - 1.f;
  __half2 p0 = __halves2half2(__float2half_rn(o.x), __float2half_rn(o.y));
  __half2 p1 = __halves2half2(__float2half_rn(o.z), __float2half_rn(o.w));
  uint2 st;
  st.x = *(unsigned*)&p0;
  st.y = *(unsigned*)&p1;
  *(uint2*)&g1[(size_t)node * 256 + lane * 4] = st;
}

// ---------------- layer-2 agg (compact [N,160] fp16 input) + head-mean + log_softmax ----
__global__ __launch_bounds__(256) void agg2_k(const __half* __restrict__ h,
                                              const int* __restrict__ rp,
                                              const int* __restrict__ srt,
                                              const float* __restrict__ b2,
                                              float* __restrict__ out, int Nn) {
  __shared__ float buf[4][160];
  int wv = threadIdx.x >> 6, lane = threadIdx.x & 63;
  int node = blockIdx.x * 4 + wv;
  if (node >= Nn) node = Nn - 1;
  const int head = lane >> 4, c4 = lane & 15;
  const bool act = c4 < 10;  // 10 lanes x 4 fp16 = 40 channels per head
  float4 xi = make_float4(0.f, 0.f, 0.f, 0.f);
  if (act) xi = ld_h4(&h[(size_t)node * 160 + head * OUTC + c4 * 4]);
  float p = xi.x * xi.x + xi.y * xi.y + xi.z * xi.z + xi.w * xi.w;
  p += __shfl_xor(p, 1); p += __shfl_xor(p, 2); p += __shfl_xor(p, 4); p += __shfl_xor(p, 8);
  float a = p > 0.f ? p : NEG * p;
  float m = a, l = 1.f;
  float4 acc = xi;
  const int e0 = rp[node], e1 = rp[node + 1];
  int e = e0;
  for (; e + 4 <= e1; e += 4) {
    int s0 = srt[e], s1 = srt[e + 1], s2 = srt[e + 2], s3 = srt[e + 3];
    float4 xj0 = make_float4(0.f, 0.f, 0.f, 0.f);
    float4 xj1 = make_float4(0.f, 0.f, 0.f, 0.f);
    float4 xj2 = make_float4(0.f, 0.f, 0.f, 0.f);
    float4 xj3 = make_float4(0.f, 0.f, 0.f, 0.f);
    if (act) {
      xj0 = ld_h4(&h[(size_t)s0 * 160 + head * OUTC + c4 * 4]);
      xj1 = ld_h4(&h[(size_t)s1 * 160 + head * OUTC + c4 * 4]);
      xj2 = ld_h4(&h[(size_t)s2 * 160 + head * OUTC + c4 * 4]);
      xj3 = ld_h4(&h[(size_t)s3 * 160 + head * OUTC + c4 * 4]);
    }
    float q0 = xi.x * xj0.x + xi.y * xj0.y + xi.z * xj0.z + xi.w * xj0.w;
    float q1 = xi.x * xj1.x + xi.y * xj1.y + xi.z * xj1.z + xi.w * xj1.w;
    float q2 = xi.x * xj2.x + xi.y * xj2.y + xi.z * xj2.z + xi.w * xj2.w;
    float q3 = xi.x * xj3.x + xi.y * xj3.y + xi.z * xj3.z + xi.w * xj3.w;
    q0 += __shfl_xor(q0, 1); q1 += __shfl_xor(q1, 1); q2 += __shfl_xor(q2, 1); q3 += __shfl_xor(q3, 1);
    q0 += __shfl_xor(q0, 2); q1 += __shfl_xor(q1, 2); q2 += __shfl_xor(q2, 2); q3 += __shfl_xor(q3, 2);
    q0 += __shfl_xor(q0, 4); q1 += __shfl_xor(q1, 4); q2 += __shfl_xor(q2, 4); q3 += __shfl_xor(q3, 4);
    q0 += __shfl_xor(q0, 8); q1 += __shfl_xor(q1, 8); q2 += __shfl_xor(q2, 8); q3 += __shfl_xor(q3, 8);
    float a0 = q0 > 0.f ? q0 : NEG * q0;
    float a1 = q1 > 0.f ? q1 : NEG * q1;
    float a2 = q2 > 0.f ? q2 : NEG * q2;
    float a3 = q3 > 0.f ? q3 : NEG * q3;
    float nm = fmaxf(fmaxf(m, fmaxf(a0, a1)), fmaxf(a2, a3));
    float sc = __expf(m - nm);
    float w0 = __expf(a0 - nm), w1 = __expf(a1 - nm);
    float w2 = __expf(a2 - nm), w3 = __expf(a3 - nm);
    l = l * sc + w0 + w1 + w2 + w3;
    acc.x = acc.x * sc + w0 * xj0.x + w1 * xj1.x + w2 * xj2.x + w3 * xj3.x;
    acc.y = acc.y * sc + w0 * xj0.y + w1 * xj1.y + w2 * xj2.y + w3 * xj3.y;
    acc.z = acc.z * sc + w0 * xj0.z + w1 * xj1.z + w2 * xj2.z + w3 * xj3.z;
    acc.w = acc.w * sc + w0 * xj0.w + w1 * xj1.w + w2 * xj2.w + w3 * xj3.w;
    m = nm;
  }
  for (; e < e1; ++e) {
    int s = srt[e];
    float4 xj = make_float4(0.f, 0.f, 0.f, 0.f);
    if (act) xj = ld_h4(&h[(size_t)s * 160 + head * OUTC + c4 * 4]);
    float q = xi.x * xj.x + xi.y * xj.y + xi.z * xj.z + xi.w * xj.w;
    q += __shfl_xor(q, 1); q += __shfl_xor(q, 2); q += __shfl_xor(q, 4); q += __shfl_xor(q, 8);
    float al = q > 0.f ? q : NEG * q;
    float nm = fmaxf(m, al);
    float sc = __expf(m - nm), wt = __expf(al - nm);
    l = l * sc + wt;
    acc.x = acc.x * sc + wt * xj.x;
    acc.y = acc.y * sc + wt * xj.y;
    acc.z = acc.z * sc + wt * xj.z;
    acc.w = acc.w * sc + wt * xj.w;
    m = nm;
  }
  float inv = 1.f / (l + EPSV);
  if (act) {
    float4 res;
    res.x = acc.x * inv; res.y = acc.y * inv; res.z = acc.z * inv; res.w = acc.w * inv;
    *(float4*)&buf[wv][head * OUTC + c4 * 4] = res;
  }
  __syncthreads();
  const bool valid = lane < OUTC;
  float v = 0.f;
  if (valid)
    v = 0.25f * (buf[wv][lane] + buf[wv][OUTC + lane] + buf[wv][2 * OUTC + lane] +
                 buf[wv][3 * OUTC + lane]) + b2[lane];
  float t = valid ? v : -1e30f;
#pragma unroll
  for (int off = 32; off; off >>= 1) t = fmaxf(t, __shfl_xor(t, off));
  float ex = valid ? __expf(v - t) : 0.f;
  float s = ex;
#pragma unroll
  for (int off = 32; off; off >>= 1) s += __shfl_xor(s, off);
  float lse = t + __logf(s);
  if (valid) out[(size_t)node * OUTC + lane] = v - lse;
  if (blockIdx.x == 0 && threadIdx.x == 0) out[(size_t)Nn * OUTC] = 0.f;  // att_loss
}

extern "C" void kernel_launch(void* const* d_in, const int* in_sizes, int n_in,
                              void* d_out, int out_size, void* d_ws, size_t ws_size,
                              hipStream_t stream) {
  const float* x  = (const float*)d_in[0];
  const int*   ei = (const int*)d_in[1];
  const float* W1 = (const float*)d_in[2];
  const float* b1 = (const float*)d_in[3];
  const float* W2 = (const float*)d_in[4];
  const float* b2 = (const float*)d_in[5];
  float* out = (float*)d_out;

  const int Nn = in_sizes[0] / 512;  // 50000
  const int E  = in_sizes[1] / 2;    // 400000
  const int* esrc = ei;
  const int* edst = ei + E;
  const int NB = (Nn + 1023) / 1024;

  // workspace layout (h region holds fp16; same reservation as before)
  char* ws = (char*)d_ws;
  const size_t szH = (size_t)Nn * 256 * sizeof(float);  // 51.2 MB reservation
  __half* h1 = (__half*)(ws);         // GEMM1 out [N,256] fp16; reused as h2 [N,160] fp16
  size_t off = szH;
  __half* g1 = (__half*)(ws + off); off += (size_t)Nn * 256 * 2;  // agg1 out, 25.6MB
  int* rp = (int*)(ws + off);   off += ((size_t)(Nn + 1) * 4 + 15) & ~(size_t)15;
  int* cnt = (int*)(ws + off);  off += ((size_t)Nn * 4 + 15) & ~(size_t)15;
  int* srt = (int*)(ws + off);  off += ((size_t)E * 4 + 15) & ~(size_t)15;
  int* bsum = (int*)(ws + off); off += 1024;
  unsigned short* Wh1 = (unsigned short*)(ws + off); off += (size_t)256 * 512 * 2;
  unsigned short* Wl1 = (unsigned short*)(ws + off); off += (size_t)256 * 512 * 2;
  unsigned short* Wh2 = (unsigned short*)(ws + off); off += (size_t)256 * 256 * 2;
  unsigned short* Wl2 = (unsigned short*)(ws + off); off += (size_t)256 * 256 * 2;
  __half* h2 = h1;

  // CSR by destination (scanC zeroes cnt for scatter's cursor)
  hipMemsetAsync(cnt, 0, (size_t)Nn * sizeof(int), stream);
  hist_k<<<(E + 255) / 256, 256, 0, stream>>>(edst, cnt, E);
  scanA_k<<<NB, 1024, 0, stream>>>(cnt, rp, bsum, Nn);
  scanC_k<<<(Nn + 255) / 256, 256, 0, stream>>>(rp, bsum, cnt, Nn, NB);
  scatter_k<<<(E + 255) / 256, 256, 0, stream>>>(esrc, edst, rp, cnt, srt, E);

  // weight pre-split (merged, fp16 hi/lo)
  convW_k<<<768, 256, 0, stream>>>(W1, Wh1, Wl1, W2, Wh2, Wl2);

  // layer 1: A = x fp32 (cvt_pkrtz at LDS read), B = fp16 Wh1/Wl1; fp16 h1 out
  gemm_dma<true, false>
      <<<dim3(2, (Nn + 127) / 128), 256, 0, stream>>>(x, Wh1, Wl1, h1, Nn, 512);
  agg1_k<<<(Nn + 3) / 4, 256, 0, stream>>>(h1, rp, srt, b1, g1, Nn);

  // layer 2: A = g1 fp16 direct, B = fp16 Wh2/Wl2; compact [N,160] fp16 out
  gemm_dma<false, true>
      <<<dim3(2, (Nn + 127) / 128), 256, 0, stream>>>(g1, Wh2, Wl2, h2, Nn, 256);
  agg2_k<<<(Nn + 3) / 4, 256, 0, stream>>>(h2, rp, srt, b2, out, Nn);
}